// Round 6
// baseline (6242.410 us; speedup 1.0000x reference)
//
#include <hip/hip_runtime.h>

constexpr int B_     = 32;
constexpr int T_     = 500;
constexpr int D_     = 3072;
constexpr int S_DEN  = 4000;
constexpr int E_DEN  = 120000;
constexpr int S_NUM  = 200;
constexpr int E_NUM  = 600;
constexpr int NCHUNK = 8;                  // den roles per utt
constexpr int EPB    = E_DEN / NCHUNK;     // 15000 target edges/role
constexpr int ECAP   = 15488;              // LDS cap (EPB + max row slack)
constexpr int NTB    = 512;                // threads per persistent block

// ============================ CSR build =====================================
__global__ void zero_ints(int* p, int n) {
    int i = blockIdx.x * 256 + threadIdx.x;
    if (i < n) p[i] = 0;
}

__global__ void hist_den(const int* __restrict__ dst, int* __restrict__ cnt) {
    int e = blockIdx.x * 256 + threadIdx.x;
    if (e < E_DEN) atomicAdd(&cnt[dst[e]], 1);
}

__global__ void hist_num(const int* __restrict__ dst, int* __restrict__ cnt) { // grid (3,32)
    int b = blockIdx.y, j = blockIdx.x * 256 + threadIdx.x;
    if (j < E_NUM) atomicAdd(&cnt[b * S_NUM + dst[b * E_NUM + j]], 1);
}

__global__ void scan_den(int* __restrict__ cnt_cur, int* __restrict__ row) { // 1 block, 1024 thr
    __shared__ int part[1024];
    int tid = threadIdx.x, base = tid * 4;
    int c[4], pre[4], s = 0;
    #pragma unroll
    for (int j = 0; j < 4; ++j) {
        int idx = base + j;
        c[j] = (idx < S_DEN) ? cnt_cur[idx] : 0;
        pre[j] = s; s += c[j];
    }
    part[tid] = s; __syncthreads();
    for (int off = 1; off < 1024; off <<= 1) {
        int v = (tid >= off) ? part[tid - off] : 0; __syncthreads();
        part[tid] += v; __syncthreads();
    }
    int offs = (tid > 0) ? part[tid - 1] : 0;
    #pragma unroll
    for (int j = 0; j < 4; ++j) {
        int idx = base + j;
        if (idx < S_DEN) { row[idx] = offs + pre[j]; cnt_cur[idx] = offs + pre[j]; }
    }
    if (tid == 1023) row[S_DEN] = part[1023];
}

__global__ void scan_num(int* __restrict__ cnt_cur, int* __restrict__ row) { // 32 blocks × 256
    __shared__ int part[256];
    int b = blockIdx.x, tid = threadIdx.x;
    int c = (tid < S_NUM) ? cnt_cur[b * S_NUM + tid] : 0;
    part[tid] = c; __syncthreads();
    for (int off = 1; off < 256; off <<= 1) {
        int v = (tid >= off) ? part[tid - off] : 0; __syncthreads();
        part[tid] += v; __syncthreads();
    }
    int excl = part[tid] - c;
    if (tid < S_NUM) { row[b * (S_NUM + 1) + tid] = excl; cnt_cur[b * S_NUM + tid] = excl; }
    if (tid == 255) row[b * (S_NUM + 1) + S_NUM] = part[255];
}

// edge payload: {src | pdf<<12, float_bits(exp(logw))} — 8 B/edge
__global__ void scatter_den(const int* __restrict__ src, const int* __restrict__ dst,
                            const int* __restrict__ pdf, const float* __restrict__ logw,
                            int* __restrict__ cur, int2* __restrict__ csr) {
    int e = blockIdx.x * 256 + threadIdx.x;
    if (e >= E_DEN) return;
    int pos = atomicAdd(&cur[dst[e]], 1);
    csr[pos] = make_int2(src[e] | (pdf[e] << 12), __float_as_int(__expf(logw[e])));
}

__global__ void scatter_num(const int* __restrict__ src, const int* __restrict__ dst,
                            const int* __restrict__ pdf, const float* __restrict__ logw,
                            int* __restrict__ cur, int2* __restrict__ csr) { // grid (3,32)
    int b = blockIdx.y, j = blockIdx.x * 256 + threadIdx.x;
    if (j >= E_NUM) return;
    int e = b * E_NUM + j;
    int pos = atomicAdd(&cur[b * S_NUM + dst[e]], 1);
    csr[b * E_NUM + pos] = make_int2(src[e] | (pdf[e] << 12), __float_as_int(__expf(logw[e])));
}

// edge-balanced state partition: part[r] = first s with row[s] >= r*EPB
__global__ void part_den(const int* __restrict__ row, int* __restrict__ part) {
    int r = threadIdx.x;                               // 1 block, 16 threads
    if (r > NCHUNK) return;
    if (r == 0)        { part[0] = 0; return; }
    if (r == NCHUNK)   { part[NCHUNK] = S_DEN; return; }
    int target = r * EPB, lo = 0, hi = S_DEN;
    while (lo < hi) { int mid = (lo + hi) >> 1; if (row[mid] < target) lo = mid + 1; else hi = mid; }
    part[r] = lo;
}

// ===================== persistent forward kernel ============================
// 256 blocks (utt b = bid&31, role r = bid>>5), 512 threads, 1 block/CU.
// Per-utt 8-block barrier via cnt[b] (monotone counter). Linear domain with
// lagged renorm identical to R5. Role 7 additionally owns the num graph
// entirely in LDS (no global traffic).
__global__ __launch_bounds__(NTB, 1)
void chain_persist(const float* __restrict__ x, const int* __restrict__ x_lengths,
                   const int* __restrict__ den_row, const int2* __restrict__ den_csr,
                   const int* __restrict__ part,
                   const int* __restrict__ num_row, const int2* __restrict__ num_csr,
                   const float* __restrict__ den_init, const float* __restrict__ den_final,
                   const float* __restrict__ num_init, const float* __restrict__ num_final,
                   float* __restrict__ EAd, float* __restrict__ Mpart,
                   float* __restrict__ Fpart, unsigned* __restrict__ cnt,
                   float* __restrict__ ll) {
    __shared__ int2   csr_d[ECAP];         // 123904 B
    __shared__ float4 ex4[D_ / 4];         //  12288 B
    __shared__ float  eal[S_DEN];          //  16000 B
    __shared__ int2   csr_n[E_NUM];        //   4800 B
    __shared__ float  eal_n[S_NUM];        //    800 B
    __shared__ float  red[8], red_n[8];
    float* ex = (float*)ex4;

    const int tid = threadIdx.x;
    const int b   = blockIdx.x & 31;
    const int r   = blockIdx.x >> 5;
    const int len = x_lengths[b];

    // --- stage den CSR chunk + per-thread row bounds (≤2 states/thread) ---
    const int s0 = part[r], s1 = part[r + 1];
    const int e0 = den_row[s0], e1 = den_row[s1];
    const int ne = e1 - e0;
    for (int i = tid; i < ne; i += NTB) csr_d[i] = den_csr[e0 + i];
    const int sa = s0 + tid, sb = s0 + tid + NTB;
    int ba = 0, eaA = 0, bb = 0, ebB = 0;
    if (sa < s1) { ba = den_row[sa] - e0; eaA = den_row[sa + 1] - e0; }
    if (sb < s1) { bb = den_row[sb] - e0; ebB = den_row[sb + 1] - e0; }
    for (int s = tid; s < S_DEN; s += NTB) eal[s] = __expf(den_init[s]);

    // --- role 7: stage num graph ---
    int nb = 0, neE = 0;
    if (r == NCHUNK - 1) {
        for (int i = tid; i < E_NUM; i += NTB) csr_n[i] = num_csr[b * E_NUM + i];
        if (tid < S_NUM) {
            nb  = num_row[b * (S_NUM + 1) + tid];
            neE = num_row[b * (S_NUM + 1) + tid + 1];
            eal_n[tid] = __expf(num_init[b * S_NUM + tid]);
        }
    }

    // --- prefetch x[b,0] into registers (768 float4/row, 512 threads) ---
    const float* xb = x + (size_t)b * T_ * D_;
    float4 xr0, xr1;
    {
        const float4* p = (const float4*)xb;
        xr0 = p[tid];
        xr1 = (tid < D_ / 4 - NTB) ? p[tid + NTB] : make_float4(0.f, 0.f, 0.f, 0.f);
    }

    float off = 0.f, offn = 0.f, acc0 = 0.f, acc1 = 0.f, accn = 0.f;

    for (int t = 0; t < len; ++t) {
        // phase A: ex = exp(x[t]) from regs; prefetch x[t+1]
        {
            float4 e0v;
            e0v.x = __expf(fminf(xr0.x, 60.f)); e0v.y = __expf(fminf(xr0.y, 60.f));
            e0v.z = __expf(fminf(xr0.z, 60.f)); e0v.w = __expf(fminf(xr0.w, 60.f));
            ex4[tid] = e0v;
            if (tid < D_ / 4 - NTB) {
                float4 e1v;
                e1v.x = __expf(fminf(xr1.x, 60.f)); e1v.y = __expf(fminf(xr1.y, 60.f));
                e1v.z = __expf(fminf(xr1.z, 60.f)); e1v.w = __expf(fminf(xr1.w, 60.f));
                ex4[tid + NTB] = e1v;
            }
            if (t + 1 < len) {
                const float4* p = (const float4*)(xb + (size_t)(t + 1) * D_);
                xr0 = p[tid];
                if (tid < D_ / 4 - NTB) xr1 = p[tid + NTB];
            }
        }
        __syncthreads();   // ex ready; also orders prev-step eal restage writes

        // phase B: den gather from LDS (csr chunk resident)
        float lmax = 0.f;
        acc0 = 0.f; acc1 = 0.f;
        if (sa < s1) {
            float a0 = 0.f, a1 = 0.f;
            int e = ba;
            for (; e + 2 <= eaA; e += 2) {
                int2 p0 = csr_d[e], p1 = csr_d[e + 1];
                a0 += eal[p0.x & 0xFFF] * __int_as_float(p0.y) * ex[p0.x >> 12];
                a1 += eal[p1.x & 0xFFF] * __int_as_float(p1.y) * ex[p1.x >> 12];
            }
            if (e < eaA) {
                int2 p0 = csr_d[e];
                a0 += eal[p0.x & 0xFFF] * __int_as_float(p0.y) * ex[p0.x >> 12];
            }
            acc0 = a0 + a1; lmax = acc0;
        }
        if (sb < s1) {
            float a0 = 0.f, a1 = 0.f;
            int e = bb;
            for (; e + 2 <= ebB; e += 2) {
                int2 p0 = csr_d[e], p1 = csr_d[e + 1];
                a0 += eal[p0.x & 0xFFF] * __int_as_float(p0.y) * ex[p0.x >> 12];
                a1 += eal[p1.x & 0xFFF] * __int_as_float(p1.y) * ex[p1.x >> 12];
            }
            if (e < ebB) {
                int2 p0 = csr_d[e];
                a0 += eal[p0.x & 0xFFF] * __int_as_float(p0.y) * ex[p0.x >> 12];
            }
            acc1 = a0 + a1; lmax = fmaxf(lmax, acc1);
        }

        // write EA_next slice to global (cross-role exchange)
        float* EAn_g = EAd + ((size_t)((t + 1) & 1) * B_ + b) * S_DEN;
        if (sa < s1) EAn_g[sa] = acc0;
        if (sb < s1) EAn_g[sb] = acc1;

        // num gather (role 7, LDS only)
        float lmax_n = 0.f;
        if (r == NCHUNK - 1 && tid < S_NUM) {
            float a = 0.f;
            for (int e = nb; e < neE; ++e) {
                int2 p0 = csr_n[e];
                a += eal_n[p0.x & 0xFFF] * __int_as_float(p0.y) * ex[p0.x >> 12];
            }
            accn = a; lmax_n = a;
        }

        // block reduce den lmax + num lmax
        #pragma unroll
        for (int o = 32; o > 0; o >>= 1) {
            lmax   = fmaxf(lmax,   __shfl_down(lmax, o));
            lmax_n = fmaxf(lmax_n, __shfl_down(lmax_n, o));
        }
        if ((tid & 63) == 0) { red[tid >> 6] = lmax; red_n[tid >> 6] = lmax_n; }
        __syncthreads();
        {
            float bm = red[0];
            #pragma unroll
            for (int w = 1; w < 8; ++w) bm = fmaxf(bm, red[w]);
            if (tid == 0) Mpart[(b * 2 + (t & 1)) * 8 + r] = bm;
        }
        if (r == NCHUNK - 1) {            // num renorm, fully local
            float Mn = red_n[0];
            #pragma unroll
            for (int w = 1; w < 8; ++w) Mn = fmaxf(Mn, red_n[w]);
            if (!(Mn > 0.f)) Mn = 1.f;
            if (tid < S_NUM) eal_n[tid] = accn / Mn;   // reads done pre-reduction sync
            offn += __logf(Mn);
        }

        // per-utt 8-block barrier (release: EAn_g + Mpart; acquire for reads)
        __syncthreads();                   // all waves' stores issued (vmcnt drained)
        if (tid == 0) {
            __threadfence();
            atomicAdd(&cnt[b], 1u);
            unsigned target = 8u * (unsigned)(t + 1);
            while (atomicAdd(&cnt[b], 0u) < target) { }
            __threadfence();
        }
        __syncthreads();

        // read group max, restage eal for next step
        if (t + 1 < len) {
            const float* mp = &Mpart[(b * 2 + (t & 1)) * 8];
            float M = fmaxf(fmaxf(fmaxf(mp[0], mp[1]), fmaxf(mp[2], mp[3])),
                            fmaxf(fmaxf(mp[4], mp[5]), fmaxf(mp[6], mp[7])));
            if (!(M > 0.f)) M = 1.f;
            off += __logf(M);
            float inv = 1.f / M;
            for (int s = tid; s < S_DEN; s += NTB) eal[s] = EAn_g[s] * inv;
        }
    }

    // --- final: den partial from last-step acc regs (un-renormed, matches off) ---
    float fs = 0.f;
    if (sa < s1) fs += acc0 * __expf(den_final[sa]);
    if (sb < s1) fs += acc1 * __expf(den_final[sb]);
    #pragma unroll
    for (int o = 32; o > 0; o >>= 1) fs += __shfl_down(fs, o);
    if ((tid & 63) == 0) red[tid >> 6] = fs;
    __syncthreads();

    float ns = (r == NCHUNK - 1 && tid < S_NUM)
             ? eal_n[tid] * __expf(num_final[b * S_NUM + tid]) : 0.f;
    #pragma unroll
    for (int o = 32; o > 0; o >>= 1) ns += __shfl_down(ns, o);
    if ((tid & 63) == 0) red_n[tid >> 6] = ns;
    __syncthreads();

    if (tid == 0) {
        float bf = 0.f;
        #pragma unroll
        for (int w = 0; w < 8; ++w) bf += red[w];
        Fpart[b * 8 + r] = bf;
        __threadfence();
        atomicAdd(&cnt[b], 1u);
        if (r == 0) {
            unsigned target = 8u * (unsigned)(len + 1);
            while (atomicAdd(&cnt[b], 0u) < target) { }
            __threadfence();
            float tot = 0.f;
            #pragma unroll
            for (int w = 0; w < 8; ++w) tot += Fpart[b * 8 + w];
            ll[b] = __logf(tot) + off;
        }
        if (r == NCHUNK - 1) {
            float tn = 0.f;
            #pragma unroll
            for (int w = 0; w < 8; ++w) tn += red_n[w];
            ll[B_ + b] = __logf(tn) + offn;
        }
    }
}

// ===================== combine ==============================================
__global__ void finalize_loss(const float* __restrict__ ll, const int* __restrict__ x_lengths,
                              float* __restrict__ out) {
    int tid = threadIdx.x;              // 64 threads, 1 block
    float d = (tid < B_) ? ll[tid] : 0.f;
    float n = (tid < B_) ? ll[B_ + tid] : 0.f;
    float l = (tid < B_) ? (float)x_lengths[tid] : 0.f;
    #pragma unroll
    for (int o = 32; o > 0; o >>= 1) {
        d += __shfl_down(d, o); n += __shfl_down(n, o); l += __shfl_down(l, o);
    }
    if (tid == 0) out[0] = (d - n) / l;
}

// ===================== fallback (no workspace) ==============================
__global__ __launch_bounds__(1024)
void chain_forward_atomic(const float* __restrict__ x, const int* __restrict__ x_lengths,
                          const int* __restrict__ den_src, const int* __restrict__ den_dst,
                          const int* __restrict__ den_pdf, const float* __restrict__ den_logw,
                          const float* __restrict__ den_init, const float* __restrict__ den_final,
                          const int* __restrict__ num_src, const int* __restrict__ num_dst,
                          const int* __restrict__ num_pdf, const float* __restrict__ num_logw,
                          const float* __restrict__ num_init, const float* __restrict__ num_final,
                          float* __restrict__ ll_out) {
    __shared__ float ea[S_DEN];
    __shared__ float ssum[S_DEN];
    __shared__ float ex[D_];
    __shared__ float red[16];
    __shared__ float s_m;
    const int  tid = threadIdx.x;
    const bool is_den = blockIdx.x < B_;
    const int  b = is_den ? blockIdx.x : blockIdx.x - B_;
    const int  S = is_den ? S_DEN : S_NUM;
    const int  E = is_den ? E_DEN : E_NUM;
    const int*   esrc = is_den ? den_src : num_src + b * E_NUM;
    const int*   edst = is_den ? den_dst : num_dst + b * E_NUM;
    const int*   epdf = is_den ? den_pdf : num_pdf + b * E_NUM;
    const float* elw  = is_den ? den_logw: num_logw + b * E_NUM;
    const float* init = is_den ? den_init : num_init + b * S_NUM;
    const float* fin  = is_den ? den_final: num_final + b * S_NUM;
    const int    len  = x_lengths[b];
    const float* xb   = x + (size_t)b * T_ * D_;
    for (int s = tid; s < S; s += 1024) { ea[s] = __expf(init[s]); ssum[s] = 0.f; }
    float off = 0.f;
    for (int t = 0; t < len; ++t) {
        const float4* xr4 = reinterpret_cast<const float4*>(xb + (size_t)t * D_);
        for (int d = tid; d < D_ / 4; d += 1024) {
            float4 v = xr4[d];
            ex[4*d+0] = __expf(fminf(v.x, 60.f)); ex[4*d+1] = __expf(fminf(v.y, 60.f));
            ex[4*d+2] = __expf(fminf(v.z, 60.f)); ex[4*d+3] = __expf(fminf(v.w, 60.f));
        }
        __syncthreads();
        for (int e = tid; e < E; e += 1024)
            unsafeAtomicAdd(&ssum[edst[e]], ea[esrc[e]] * __expf(elw[e]) * ex[epdf[e]]);
        __syncthreads();
        float lm = 0.f;
        for (int s = tid; s < S; s += 1024) lm = fmaxf(lm, ssum[s]);
        #pragma unroll
        for (int o = 32; o > 0; o >>= 1) lm = fmaxf(lm, __shfl_down(lm, o));
        if ((tid & 63) == 0) red[tid >> 6] = lm;
        __syncthreads();
        if (tid == 0) {
            float m = red[0];
            for (int w = 1; w < 16; ++w) m = fmaxf(m, red[w]);
            s_m = (m > 0.f) ? m : 1.f;
        }
        __syncthreads();
        float inv = 1.f / s_m;
        off += __logf(s_m);
        for (int s = tid; s < S; s += 1024) { ea[s] = ssum[s] * inv; ssum[s] = 0.f; }
    }
    float lsum = 0.f;
    for (int s = tid; s < S; s += 1024) lsum += ea[s] * __expf(fin[s]);
    #pragma unroll
    for (int o = 32; o > 0; o >>= 1) lsum += __shfl_down(lsum, o);
    if ((tid & 63) == 0) red[tid >> 6] = lsum;
    __syncthreads();
    if (tid == 0) {
        float tot = 0.f;
        for (int w = 0; w < 16; ++w) tot += red[w];
        ll_out[blockIdx.x] = off + __logf(tot);
    }
}

static inline size_t align16(size_t v) { return (v + 15) & ~size_t(15); }

extern "C" void kernel_launch(void* const* d_in, const int* in_sizes, int n_in,
                              void* d_out, int out_size, void* d_ws, size_t ws_size,
                              hipStream_t stream) {
    const float* x         = (const float*)d_in[0];
    const int*   x_lengths = (const int*)  d_in[1];
    const int*   den_src   = (const int*)  d_in[2];
    const int*   den_dst   = (const int*)  d_in[3];
    const int*   den_pdf   = (const int*)  d_in[4];
    const float* den_logw  = (const float*)d_in[5];
    const float* den_init  = (const float*)d_in[6];
    const float* den_final = (const float*)d_in[7];
    const int*   num_src   = (const int*)  d_in[8];
    const int*   num_dst   = (const int*)  d_in[9];
    const int*   num_pdf   = (const int*)  d_in[10];
    const float* num_logw  = (const float*)d_in[11];
    const float* num_init  = (const float*)d_in[12];
    const float* num_final = (const float*)d_in[13];

    char* ws = (char*)d_ws;
    size_t o = 0;
    float*    ll      = (float*)   (ws + o); o = align16(o + 64 * sizeof(float));
    int*      den_row = (int*)     (ws + o); o = align16(o + (S_DEN + 1) * sizeof(int));
    int*      den_cur = (int*)     (ws + o); o = align16(o + S_DEN * sizeof(int));
    int*      num_row = (int*)     (ws + o); o = align16(o + B_ * (S_NUM + 1) * sizeof(int));
    int*      num_cur = (int*)     (ws + o); o = align16(o + B_ * S_NUM * sizeof(int));
    int2*     den_csr = (int2*)    (ws + o); o = align16(o + (size_t)E_DEN * sizeof(int2));
    int2*     num_csr = (int2*)    (ws + o); o = align16(o + (size_t)B_ * E_NUM * sizeof(int2));
    int*      part    = (int*)     (ws + o); o = align16(o + (NCHUNK + 1) * sizeof(int));
    float*    EAd     = (float*)   (ws + o); o = align16(o + (size_t)2 * B_ * S_DEN * sizeof(float));
    float*    Mpart   = (float*)   (ws + o); o = align16(o + (size_t)B_ * 2 * 8 * sizeof(float));
    float*    Fpart   = (float*)   (ws + o); o = align16(o + (size_t)B_ * 8 * sizeof(float));
    unsigned* cnt     = (unsigned*)(ws + o); o = align16(o + B_ * sizeof(unsigned));
    const size_t need = o;

    if (ws_size >= need) {
        zero_ints<<<(S_DEN + 255) / 256, 256, 0, stream>>>(den_cur, S_DEN);
        zero_ints<<<(B_ * S_NUM + 255) / 256, 256, 0, stream>>>(num_cur, B_ * S_NUM);
        zero_ints<<<1, 256, 0, stream>>>((int*)cnt, B_);
        hist_den<<<(E_DEN + 255) / 256, 256, 0, stream>>>(den_dst, den_cur);
        hist_num<<<dim3(3, B_), 256, 0, stream>>>(num_dst, num_cur);
        scan_den<<<1, 1024, 0, stream>>>(den_cur, den_row);
        scan_num<<<B_, 256, 0, stream>>>(num_cur, num_row);
        scatter_den<<<(E_DEN + 255) / 256, 256, 0, stream>>>(
            den_src, den_dst, den_pdf, den_logw, den_cur, den_csr);
        scatter_num<<<dim3(3, B_), 256, 0, stream>>>(
            num_src, num_dst, num_pdf, num_logw, num_cur, num_csr);
        part_den<<<1, 16, 0, stream>>>(den_row, part);

        void* args[] = {
            (void*)&x, (void*)&x_lengths, (void*)&den_row, (void*)&den_csr, (void*)&part,
            (void*)&num_row, (void*)&num_csr, (void*)&den_init, (void*)&den_final,
            (void*)&num_init, (void*)&num_final, (void*)&EAd, (void*)&Mpart,
            (void*)&Fpart, (void*)&cnt, (void*)&ll
        };
        hipError_t err = hipLaunchCooperativeKernel((const void*)chain_persist,
                                                    dim3(B_ * NCHUNK), dim3(NTB),
                                                    args, 0, stream);
        if (err != hipSuccess) {
            // same config, 1 block/CU forced by 158 KB LDS -> de-facto co-resident
            chain_persist<<<dim3(B_ * NCHUNK), dim3(NTB), 0, stream>>>(
                x, x_lengths, den_row, den_csr, part, num_row, num_csr,
                den_init, den_final, num_init, num_final,
                EAd, Mpart, Fpart, cnt, ll);
        }
        finalize_loss<<<1, 64, 0, stream>>>(ll, x_lengths, (float*)d_out);
    } else {
        chain_forward_atomic<<<2 * B_, 1024, 0, stream>>>(
            x, x_lengths, den_src, den_dst, den_pdf, den_logw, den_init, den_final,
            num_src, num_dst, num_pdf, num_logw, num_init, num_final, ll);
        finalize_loss<<<1, 64, 0, stream>>>(ll, x_lengths, (float*)d_out);
    }
}

// Round 7
// 3823.356 us; speedup vs baseline: 1.6327x; 1.6327x over previous
//
#include <hip/hip_runtime.h>

constexpr int B_     = 32;
constexpr int T_     = 500;
constexpr int D_     = 3072;
constexpr int S_DEN  = 4000;
constexpr int E_DEN  = 120000;
constexpr int S_NUM  = 200;
constexpr int E_NUM  = 600;
constexpr int NCHUNK = 8;                  // den roles per utt
constexpr int EPB    = E_DEN / NCHUNK;     // 15000 target edges/role
constexpr int ECAP   = 15488;              // LDS cap (EPB + max row slack)
constexpr int NTB    = 512;                // threads per persistent block
constexpr int FLAGS_PER_UTT = 16;          // 2 parities x 8 roles, 128B/utt

// ============================ CSR build =====================================
__global__ void zero_ints(int* p, int n) {
    int i = blockIdx.x * 256 + threadIdx.x;
    if (i < n) p[i] = 0;
}

__global__ void hist_den(const int* __restrict__ dst, int* __restrict__ cnt) {
    int e = blockIdx.x * 256 + threadIdx.x;
    if (e < E_DEN) atomicAdd(&cnt[dst[e]], 1);
}

__global__ void hist_num(const int* __restrict__ dst, int* __restrict__ cnt) { // grid (3,32)
    int b = blockIdx.y, j = blockIdx.x * 256 + threadIdx.x;
    if (j < E_NUM) atomicAdd(&cnt[b * S_NUM + dst[b * E_NUM + j]], 1);
}

__global__ void scan_den(int* __restrict__ cnt_cur, int* __restrict__ row) { // 1 block, 1024 thr
    __shared__ int part[1024];
    int tid = threadIdx.x, base = tid * 4;
    int c[4], pre[4], s = 0;
    #pragma unroll
    for (int j = 0; j < 4; ++j) {
        int idx = base + j;
        c[j] = (idx < S_DEN) ? cnt_cur[idx] : 0;
        pre[j] = s; s += c[j];
    }
    part[tid] = s; __syncthreads();
    for (int off = 1; off < 1024; off <<= 1) {
        int v = (tid >= off) ? part[tid - off] : 0; __syncthreads();
        part[tid] += v; __syncthreads();
    }
    int offs = (tid > 0) ? part[tid - 1] : 0;
    #pragma unroll
    for (int j = 0; j < 4; ++j) {
        int idx = base + j;
        if (idx < S_DEN) { row[idx] = offs + pre[j]; cnt_cur[idx] = offs + pre[j]; }
    }
    if (tid == 1023) row[S_DEN] = part[1023];
}

__global__ void scan_num(int* __restrict__ cnt_cur, int* __restrict__ row) { // 32 blocks × 256
    __shared__ int part[256];
    int b = blockIdx.x, tid = threadIdx.x;
    int c = (tid < S_NUM) ? cnt_cur[b * S_NUM + tid] : 0;
    part[tid] = c; __syncthreads();
    for (int off = 1; off < 256; off <<= 1) {
        int v = (tid >= off) ? part[tid - off] : 0; __syncthreads();
        part[tid] += v; __syncthreads();
    }
    int excl = part[tid] - c;
    if (tid < S_NUM) { row[b * (S_NUM + 1) + tid] = excl; cnt_cur[b * S_NUM + tid] = excl; }
    if (tid == 255) row[b * (S_NUM + 1) + S_NUM] = part[255];
}

// edge payload: {src | pdf<<12, float_bits(exp(logw))} — 8 B/edge
__global__ void scatter_den(const int* __restrict__ src, const int* __restrict__ dst,
                            const int* __restrict__ pdf, const float* __restrict__ logw,
                            int* __restrict__ cur, int2* __restrict__ csr) {
    int e = blockIdx.x * 256 + threadIdx.x;
    if (e >= E_DEN) return;
    int pos = atomicAdd(&cur[dst[e]], 1);
    csr[pos] = make_int2(src[e] | (pdf[e] << 12), __float_as_int(__expf(logw[e])));
}

__global__ void scatter_num(const int* __restrict__ src, const int* __restrict__ dst,
                            const int* __restrict__ pdf, const float* __restrict__ logw,
                            int* __restrict__ cur, int2* __restrict__ csr) { // grid (3,32)
    int b = blockIdx.y, j = blockIdx.x * 256 + threadIdx.x;
    if (j >= E_NUM) return;
    int e = b * E_NUM + j;
    int pos = atomicAdd(&cur[b * S_NUM + dst[e]], 1);
    csr[b * E_NUM + pos] = make_int2(src[e] | (pdf[e] << 12), __float_as_int(__expf(logw[e])));
}

// edge-balanced state partition: part[r] = first s with row[s] >= r*EPB
__global__ void part_den(const int* __restrict__ row, int* __restrict__ part) {
    int r = threadIdx.x;                               // 1 block, 16 threads
    if (r > NCHUNK) return;
    if (r == 0)        { part[0] = 0; return; }
    if (r == NCHUNK)   { part[NCHUNK] = S_DEN; return; }
    int target = r * EPB, lo = 0, hi = S_DEN;
    while (lo < hi) { int mid = (lo + hi) >> 1; if (row[mid] < target) lo = mid + 1; else hi = mid; }
    part[r] = lo;
}

// ===================== persistent forward kernel ============================
// 256 blocks (utt b = bid&31, role r = bid>>5), 512 threads, 1 block/CU.
// Per-utt sync fused into the max-exchange: each role release-stores an 8B
// flag {tag=t+1, M_role}; readers poll with agent-scope relaxed loads (no
// RMW), take the max from the payloads. Alpha exchanged via agent-scope (sc1)
// stores + one reader-side threadfence (inv) before coalesced plain reloads.
__global__ __launch_bounds__(NTB, 1)
void chain_persist(const float* __restrict__ x, const int* __restrict__ x_lengths,
                   const int* __restrict__ den_row, const int2* __restrict__ den_csr,
                   const int* __restrict__ part,
                   const int* __restrict__ num_row, const int2* __restrict__ num_csr,
                   const float* __restrict__ den_init, const float* __restrict__ den_final,
                   const float* __restrict__ num_init, const float* __restrict__ num_final,
                   float* __restrict__ EAd,
                   unsigned long long* __restrict__ Mflag,
                   unsigned long long* __restrict__ Fflag,
                   float* __restrict__ ll) {
    __shared__ int2   csr_d[ECAP];         // 123904 B
    __shared__ float4 ex4[D_ / 4];         //  12288 B
    __shared__ float  eal[S_DEN];          //  16000 B
    __shared__ int2   csr_n[E_NUM];        //   4800 B
    __shared__ float  eal_n[S_NUM];        //    800 B
    __shared__ float  red[8], red_n[8];
    __shared__ float  s_m;
    float* ex = (float*)ex4;

    const int tid = threadIdx.x;
    const int b   = blockIdx.x & 31;
    const int r   = blockIdx.x >> 5;
    const int len = x_lengths[b];

    // --- stage den CSR chunk + per-thread row bounds (≤2 states/thread) ---
    const int s0 = part[r], s1 = part[r + 1];
    const int e0 = den_row[s0], e1 = den_row[s1];
    const int ne = e1 - e0;
    for (int i = tid; i < ne; i += NTB) csr_d[i] = den_csr[e0 + i];
    const int sa = s0 + tid, sb = s0 + tid + NTB;
    int ba = 0, eaA = 0, bb = 0, ebB = 0;
    if (sa < s1) { ba = den_row[sa] - e0; eaA = den_row[sa + 1] - e0; }
    if (sb < s1) { bb = den_row[sb] - e0; ebB = den_row[sb + 1] - e0; }
    for (int s = tid; s < S_DEN; s += NTB) eal[s] = __expf(den_init[s]);

    // --- role 7: stage num graph ---
    int nb = 0, neE = 0;
    if (r == NCHUNK - 1) {
        for (int i = tid; i < E_NUM; i += NTB) csr_n[i] = num_csr[b * E_NUM + i];
        if (tid < S_NUM) {
            nb  = num_row[b * (S_NUM + 1) + tid];
            neE = num_row[b * (S_NUM + 1) + tid + 1];
            eal_n[tid] = __expf(num_init[b * S_NUM + tid]);
        }
    }

    // --- prefetch x[b,0] into registers (768 float4/row, 512 threads) ---
    const float* xb = x + (size_t)b * T_ * D_;
    float4 xr0, xr1;
    {
        const float4* p = (const float4*)xb;
        xr0 = p[tid];
        xr1 = (tid < D_ / 4 - NTB) ? p[tid + NTB] : make_float4(0.f, 0.f, 0.f, 0.f);
    }

    float off = 0.f, offn = 0.f, acc0 = 0.f, acc1 = 0.f, accn = 0.f;
    unsigned long long* uflag = Mflag + (size_t)b * FLAGS_PER_UTT;   // [parity][role]

    for (int t = 0; t < len; ++t) {
        // phase A: ex = exp(x[t]) from regs; prefetch x[t+1]
        {
            float4 e0v;
            e0v.x = __expf(fminf(xr0.x, 60.f)); e0v.y = __expf(fminf(xr0.y, 60.f));
            e0v.z = __expf(fminf(xr0.z, 60.f)); e0v.w = __expf(fminf(xr0.w, 60.f));
            ex4[tid] = e0v;
            if (tid < D_ / 4 - NTB) {
                float4 e1v;
                e1v.x = __expf(fminf(xr1.x, 60.f)); e1v.y = __expf(fminf(xr1.y, 60.f));
                e1v.z = __expf(fminf(xr1.z, 60.f)); e1v.w = __expf(fminf(xr1.w, 60.f));
                ex4[tid + NTB] = e1v;
            }
            if (t + 1 < len) {
                const float4* p = (const float4*)(xb + (size_t)(t + 1) * D_);
                xr0 = p[tid];
                if (tid < D_ / 4 - NTB) xr1 = p[tid + NTB];
            }
        }
        __syncthreads();   // ex ready; also orders prev-step eal restage writes

        // phase B: den gather from LDS (csr chunk resident)
        float lmax = 0.f;
        acc0 = 0.f; acc1 = 0.f;
        if (sa < s1) {
            float a0 = 0.f, a1 = 0.f;
            int e = ba;
            for (; e + 2 <= eaA; e += 2) {
                int2 p0 = csr_d[e], p1 = csr_d[e + 1];
                a0 += eal[p0.x & 0xFFF] * __int_as_float(p0.y) * ex[p0.x >> 12];
                a1 += eal[p1.x & 0xFFF] * __int_as_float(p1.y) * ex[p1.x >> 12];
            }
            if (e < eaA) {
                int2 p0 = csr_d[e];
                a0 += eal[p0.x & 0xFFF] * __int_as_float(p0.y) * ex[p0.x >> 12];
            }
            acc0 = a0 + a1; lmax = acc0;
        }
        if (sb < s1) {
            float a0 = 0.f, a1 = 0.f;
            int e = bb;
            for (; e + 2 <= ebB; e += 2) {
                int2 p0 = csr_d[e], p1 = csr_d[e + 1];
                a0 += eal[p0.x & 0xFFF] * __int_as_float(p0.y) * ex[p0.x >> 12];
                a1 += eal[p1.x & 0xFFF] * __int_as_float(p1.y) * ex[p1.x >> 12];
            }
            if (e < ebB) {
                int2 p0 = csr_d[e];
                a0 += eal[p0.x & 0xFFF] * __int_as_float(p0.y) * ex[p0.x >> 12];
            }
            acc1 = a0 + a1; lmax = fmaxf(lmax, acc1);
        }

        // write EA_next slice (agent-scope sc1 stores: visible without fence)
        float* EAn_g = EAd + ((size_t)((t + 1) & 1) * B_ + b) * S_DEN;
        if (sa < s1) __hip_atomic_store(&EAn_g[sa], acc0, __ATOMIC_RELAXED, __HIP_MEMORY_SCOPE_AGENT);
        if (sb < s1) __hip_atomic_store(&EAn_g[sb], acc1, __ATOMIC_RELAXED, __HIP_MEMORY_SCOPE_AGENT);

        // num gather (role 7, LDS only)
        float lmax_n = 0.f;
        if (r == NCHUNK - 1 && tid < S_NUM) {
            float a = 0.f;
            for (int e = nb; e < neE; ++e) {
                int2 p0 = csr_n[e];
                a += eal_n[p0.x & 0xFFF] * __int_as_float(p0.y) * ex[p0.x >> 12];
            }
            accn = a; lmax_n = a;
        }

        // block reduce den lmax + num lmax
        #pragma unroll
        for (int o = 32; o > 0; o >>= 1) {
            lmax   = fmaxf(lmax,   __shfl_down(lmax, o));
            lmax_n = fmaxf(lmax_n, __shfl_down(lmax_n, o));
        }
        if ((tid & 63) == 0) { red[tid >> 6] = lmax; red_n[tid >> 6] = lmax_n; }
        __syncthreads();                       // also drains EAn_g stores (vmcnt)

        if (r == NCHUNK - 1) {                 // num renorm, fully local
            float Mn = red_n[0];
            #pragma unroll
            for (int w = 1; w < 8; ++w) Mn = fmaxf(Mn, red_n[w]);
            if (!(Mn > 0.f)) Mn = 1.f;
            if (tid < S_NUM) eal_n[tid] = accn / Mn;
            offn += __logf(Mn);
        }

        if (t + 1 < len) {
            // publish {tag=t+1, role max} — the barrier IS this flag
            if (tid == 0) {
                float bm = red[0];
                #pragma unroll
                for (int w = 1; w < 8; ++w) bm = fmaxf(bm, red[w]);
                unsigned long long pv =
                    ((unsigned long long)(unsigned)(t + 1) << 32) |
                    (unsigned long long)__float_as_uint(bm);
                __hip_atomic_store(&uflag[(t & 1) * 8 + r], pv,
                                   __ATOMIC_RELEASE, __HIP_MEMORY_SCOPE_AGENT);
            }
            // wave 0 polls the 8 role flags (relaxed sc1 loads, no RMW)
            if (tid < 64) {
                unsigned long long* slots = &uflag[(t & 1) * 8];
                float mv = 0.f;
                bool rdy = (tid >= 8);
                const unsigned want = (unsigned)(t + 1);
                while (true) {
                    if (!rdy) {
                        unsigned long long v = __hip_atomic_load(&slots[tid],
                                                 __ATOMIC_RELAXED, __HIP_MEMORY_SCOPE_AGENT);
                        if ((unsigned)(v >> 32) == want) {
                            rdy = true; mv = __uint_as_float((unsigned)v);
                        }
                    }
                    if (__all(rdy)) break;
                    __builtin_amdgcn_s_sleep(1);
                }
                #pragma unroll
                for (int o = 4; o > 0; o >>= 1) mv = fmaxf(mv, __shfl_down(mv, o));
                if (tid == 0) {
                    __threadfence();           // inv caches -> fresh EAn_g below
                    s_m = (mv > 0.f) ? mv : 1.f;
                }
            }
            __syncthreads();

            float M = s_m;
            off += __logf(M);
            float inv = 1.f / M;
            const float4* g4 = (const float4*)EAn_g;
            float4* e4 = (float4*)eal;
            float4 v0 = g4[tid];
            const bool has2 = (tid + NTB) < (S_DEN / 4);
            float4 v1;
            if (has2) v1 = g4[tid + NTB];
            v0.x *= inv; v0.y *= inv; v0.z *= inv; v0.w *= inv;
            e4[tid] = v0;
            if (has2) {
                v1.x *= inv; v1.y *= inv; v1.z *= inv; v1.w *= inv;
                e4[tid + NTB] = v1;
            }
            // next iteration's phase-A __syncthreads orders eal writes vs reads
        }
    }

    // --- final: den partial from last-step acc regs (un-renormed, matches off) ---
    float fs = 0.f;
    if (sa < s1) fs += acc0 * __expf(den_final[sa]);
    if (sb < s1) fs += acc1 * __expf(den_final[sb]);
    #pragma unroll
    for (int o = 32; o > 0; o >>= 1) fs += __shfl_down(fs, o);
    if ((tid & 63) == 0) red[tid >> 6] = fs;
    __syncthreads();

    if (tid == 0) {
        float bf = 0.f;
        #pragma unroll
        for (int w = 0; w < 8; ++w) bf += red[w];
        unsigned long long pv = ((unsigned long long)(unsigned)len << 32) |
                                (unsigned long long)__float_as_uint(bf);
        __hip_atomic_store(&Fflag[b * 8 + r], pv, __ATOMIC_RELEASE, __HIP_MEMORY_SCOPE_AGENT);
    }

    if (r == 0 && tid < 64) {                  // den ll: role 0 gathers 8 partials
        float sv = 0.f;
        bool rdy = (tid >= 8);
        const unsigned want = (unsigned)len;
        while (true) {
            if (!rdy) {
                unsigned long long v = __hip_atomic_load(&Fflag[b * 8 + tid],
                                         __ATOMIC_RELAXED, __HIP_MEMORY_SCOPE_AGENT);
                if ((unsigned)(v >> 32) == want) { rdy = true; sv = __uint_as_float((unsigned)v); }
            }
            if (__all(rdy)) break;
            __builtin_amdgcn_s_sleep(1);
        }
        #pragma unroll
        for (int o = 4; o > 0; o >>= 1) sv += __shfl_down(sv, o);
        if (tid == 0) ll[b] = __logf(sv) + off;
    }

    if (r == NCHUNK - 1) {                     // num ll: fully local to role 7
        float ns = (tid < S_NUM) ? eal_n[tid] * __expf(num_final[b * S_NUM + tid]) : 0.f;
        #pragma unroll
        for (int o = 32; o > 0; o >>= 1) ns += __shfl_down(ns, o);
        if ((tid & 63) == 0) red_n[tid >> 6] = ns;
        __syncthreads();
        if (tid == 0) {
            float tn = 0.f;
            #pragma unroll
            for (int w = 0; w < 8; ++w) tn += red_n[w];
            ll[B_ + b] = __logf(tn) + offn;
        }
    }
}

// ===================== combine ==============================================
__global__ void finalize_loss(const float* __restrict__ ll, const int* __restrict__ x_lengths,
                              float* __restrict__ out) {
    int tid = threadIdx.x;              // 64 threads, 1 block
    float d = (tid < B_) ? ll[tid] : 0.f;
    float n = (tid < B_) ? ll[B_ + tid] : 0.f;
    float l = (tid < B_) ? (float)x_lengths[tid] : 0.f;
    #pragma unroll
    for (int o = 32; o > 0; o >>= 1) {
        d += __shfl_down(d, o); n += __shfl_down(n, o); l += __shfl_down(l, o);
    }
    if (tid == 0) out[0] = (d - n) / l;
}

// ===================== fallback (no workspace) ==============================
__global__ __launch_bounds__(1024)
void chain_forward_atomic(const float* __restrict__ x, const int* __restrict__ x_lengths,
                          const int* __restrict__ den_src, const int* __restrict__ den_dst,
                          const int* __restrict__ den_pdf, const float* __restrict__ den_logw,
                          const float* __restrict__ den_init, const float* __restrict__ den_final,
                          const int* __restrict__ num_src, const int* __restrict__ num_dst,
                          const int* __restrict__ num_pdf, const float* __restrict__ num_logw,
                          const float* __restrict__ num_init, const float* __restrict__ num_final,
                          float* __restrict__ ll_out) {
    __shared__ float ea[S_DEN];
    __shared__ float ssum[S_DEN];
    __shared__ float ex[D_];
    __shared__ float red[16];
    __shared__ float s_m;
    const int  tid = threadIdx.x;
    const bool is_den = blockIdx.x < B_;
    const int  b = is_den ? blockIdx.x : blockIdx.x - B_;
    const int  S = is_den ? S_DEN : S_NUM;
    const int  E = is_den ? E_DEN : E_NUM;
    const int*   esrc = is_den ? den_src : num_src + b * E_NUM;
    const int*   edst = is_den ? den_dst : num_dst + b * E_NUM;
    const int*   epdf = is_den ? den_pdf : num_pdf + b * E_NUM;
    const float* elw  = is_den ? den_logw: num_logw + b * E_NUM;
    const float* init = is_den ? den_init : num_init + b * S_NUM;
    const float* fin  = is_den ? den_final: num_final + b * S_NUM;
    const int    len  = x_lengths[b];
    const float* xb   = x + (size_t)b * T_ * D_;
    for (int s = tid; s < S; s += 1024) { ea[s] = __expf(init[s]); ssum[s] = 0.f; }
    float off = 0.f;
    for (int t = 0; t < len; ++t) {
        const float4* xr4 = reinterpret_cast<const float4*>(xb + (size_t)t * D_);
        for (int d = tid; d < D_ / 4; d += 1024) {
            float4 v = xr4[d];
            ex[4*d+0] = __expf(fminf(v.x, 60.f)); ex[4*d+1] = __expf(fminf(v.y, 60.f));
            ex[4*d+2] = __expf(fminf(v.z, 60.f)); ex[4*d+3] = __expf(fminf(v.w, 60.f));
        }
        __syncthreads();
        for (int e = tid; e < E; e += 1024)
            unsafeAtomicAdd(&ssum[edst[e]], ea[esrc[e]] * __expf(elw[e]) * ex[epdf[e]]);
        __syncthreads();
        float lm = 0.f;
        for (int s = tid; s < S; s += 1024) lm = fmaxf(lm, ssum[s]);
        #pragma unroll
        for (int o = 32; o > 0; o >>= 1) lm = fmaxf(lm, __shfl_down(lm, o));
        if ((tid & 63) == 0) red[tid >> 6] = lm;
        __syncthreads();
        if (tid == 0) {
            float m = red[0];
            for (int w = 1; w < 16; ++w) m = fmaxf(m, red[w]);
            s_m = (m > 0.f) ? m : 1.f;
        }
        __syncthreads();
        float inv = 1.f / s_m;
        off += __logf(s_m);
        for (int s = tid; s < S; s += 1024) { ea[s] = ssum[s] * inv; ssum[s] = 0.f; }
    }
    float lsum = 0.f;
    for (int s = tid; s < S; s += 1024) lsum += ea[s] * __expf(fin[s]);
    #pragma unroll
    for (int o = 32; o > 0; o >>= 1) lsum += __shfl_down(lsum, o);
    if ((tid & 63) == 0) red[tid >> 6] = lsum;
    __syncthreads();
    if (tid == 0) {
        float tot = 0.f;
        for (int w = 0; w < 16; ++w) tot += red[w];
        ll_out[blockIdx.x] = off + __logf(tot);
    }
}

static inline size_t align16(size_t v) { return (v + 15) & ~size_t(15); }

extern "C" void kernel_launch(void* const* d_in, const int* in_sizes, int n_in,
                              void* d_out, int out_size, void* d_ws, size_t ws_size,
                              hipStream_t stream) {
    const float* x         = (const float*)d_in[0];
    const int*   x_lengths = (const int*)  d_in[1];
    const int*   den_src   = (const int*)  d_in[2];
    const int*   den_dst   = (const int*)  d_in[3];
    const int*   den_pdf   = (const int*)  d_in[4];
    const float* den_logw  = (const float*)d_in[5];
    const float* den_init  = (const float*)d_in[6];
    const float* den_final = (const float*)d_in[7];
    const int*   num_src   = (const int*)  d_in[8];
    const int*   num_dst   = (const int*)  d_in[9];
    const int*   num_pdf   = (const int*)  d_in[10];
    const float* num_logw  = (const float*)d_in[11];
    const float* num_init  = (const float*)d_in[12];
    const float* num_final = (const float*)d_in[13];

    char* ws = (char*)d_ws;
    size_t o = 0;
    float*              ll      = (float*)             (ws + o); o = align16(o + 64 * sizeof(float));
    int*                den_row = (int*)               (ws + o); o = align16(o + (S_DEN + 1) * sizeof(int));
    int*                den_cur = (int*)               (ws + o); o = align16(o + S_DEN * sizeof(int));
    int*                num_row = (int*)               (ws + o); o = align16(o + B_ * (S_NUM + 1) * sizeof(int));
    int*                num_cur = (int*)               (ws + o); o = align16(o + B_ * S_NUM * sizeof(int));
    int2*               den_csr = (int2*)              (ws + o); o = align16(o + (size_t)E_DEN * sizeof(int2));
    int2*               num_csr = (int2*)              (ws + o); o = align16(o + (size_t)B_ * E_NUM * sizeof(int2));
    int*                part    = (int*)               (ws + o); o = align16(o + (NCHUNK + 1) * sizeof(int));
    float*              EAd     = (float*)             (ws + o); o = align16(o + (size_t)2 * B_ * S_DEN * sizeof(float));
    unsigned long long* Mflag   = (unsigned long long*)(ws + o); o = align16(o + (size_t)B_ * FLAGS_PER_UTT * sizeof(unsigned long long));
    unsigned long long* Fflag   = (unsigned long long*)(ws + o); o = align16(o + (size_t)B_ * 8 * sizeof(unsigned long long));
    const size_t need = o;

    if (ws_size >= need) {
        zero_ints<<<(S_DEN + 255) / 256, 256, 0, stream>>>(den_cur, S_DEN);
        zero_ints<<<(B_ * S_NUM + 255) / 256, 256, 0, stream>>>(num_cur, B_ * S_NUM);
        hist_den<<<(E_DEN + 255) / 256, 256, 0, stream>>>(den_dst, den_cur);
        hist_num<<<dim3(3, B_), 256, 0, stream>>>(num_dst, num_cur);
        scan_den<<<1, 1024, 0, stream>>>(den_cur, den_row);
        scan_num<<<B_, 256, 0, stream>>>(num_cur, num_row);
        scatter_den<<<(E_DEN + 255) / 256, 256, 0, stream>>>(
            den_src, den_dst, den_pdf, den_logw, den_cur, den_csr);
        scatter_num<<<dim3(3, B_), 256, 0, stream>>>(
            num_src, num_dst, num_pdf, num_logw, num_cur, num_csr);
        part_den<<<1, 16, 0, stream>>>(den_row, part);

        void* args[] = {
            (void*)&x, (void*)&x_lengths, (void*)&den_row, (void*)&den_csr, (void*)&part,
            (void*)&num_row, (void*)&num_csr, (void*)&den_init, (void*)&den_final,
            (void*)&num_init, (void*)&num_final, (void*)&EAd, (void*)&Mflag,
            (void*)&Fflag, (void*)&ll
        };
        hipError_t err = hipLaunchCooperativeKernel((const void*)chain_persist,
                                                    dim3(B_ * NCHUNK), dim3(NTB),
                                                    args, 0, stream);
        if (err != hipSuccess) {
            // same config, 1 block/CU forced by 158 KB LDS -> de-facto co-resident
            chain_persist<<<dim3(B_ * NCHUNK), dim3(NTB), 0, stream>>>(
                x, x_lengths, den_row, den_csr, part, num_row, num_csr,
                den_init, den_final, num_init, num_final,
                EAd, Mflag, Fflag, ll);
        }
        finalize_loss<<<1, 64, 0, stream>>>(ll, x_lengths, (float*)d_out);
    } else {
        chain_forward_atomic<<<2 * B_, 1024, 0, stream>>>(
            x, x_lengths, den_src, den_dst, den_pdf, den_logw, den_init, den_final,
            num_src, num_dst, num_pdf, num_logw, num_init, num_final, ll);
        finalize_loss<<<1, 64, 0, stream>>>(ll, x_lengths, (float*)d_out);
    }
}

// Round 8
// 3671.417 us; speedup vs baseline: 1.7003x; 1.0414x over previous
//
#include <hip/hip_runtime.h>

constexpr int B_     = 32;
constexpr int T_     = 500;
constexpr int D_     = 3072;
constexpr int S_DEN  = 4000;
constexpr int E_DEN  = 120000;
constexpr int S_NUM  = 200;
constexpr int E_NUM  = 600;
constexpr int NCHUNK = 8;                  // den roles per utt
constexpr int WTGT   = (E_DEN + 2 * E_NUM) / NCHUNK;  // 15150: role 7 gets fewer den edges
constexpr int ECAP   = 15488;              // LDS cap (WTGT + row slack)
constexpr int NTB    = 512;                // threads per persistent block
constexpr int FLAGS_PER_UTT = 16;          // 2 parities x 8 roles, 128B/utt

// ============================ CSR build =====================================
__global__ void zero_ints(int* p, int n) {
    int i = blockIdx.x * 256 + threadIdx.x;
    if (i < n) p[i] = 0;
}

__global__ void hist_den(const int* __restrict__ dst, int* __restrict__ cnt) {
    int e = blockIdx.x * 256 + threadIdx.x;
    if (e < E_DEN) atomicAdd(&cnt[dst[e]], 1);
}

__global__ void hist_num(const int* __restrict__ dst, int* __restrict__ cnt) { // grid (3,32)
    int b = blockIdx.y, j = blockIdx.x * 256 + threadIdx.x;
    if (j < E_NUM) atomicAdd(&cnt[b * S_NUM + dst[b * E_NUM + j]], 1);
}

__global__ void scan_den(int* __restrict__ cnt_cur, int* __restrict__ row) { // 1 block, 1024 thr
    __shared__ int part[1024];
    int tid = threadIdx.x, base = tid * 4;
    int c[4], pre[4], s = 0;
    #pragma unroll
    for (int j = 0; j < 4; ++j) {
        int idx = base + j;
        c[j] = (idx < S_DEN) ? cnt_cur[idx] : 0;
        pre[j] = s; s += c[j];
    }
    part[tid] = s; __syncthreads();
    for (int off = 1; off < 1024; off <<= 1) {
        int v = (tid >= off) ? part[tid - off] : 0; __syncthreads();
        part[tid] += v; __syncthreads();
    }
    int offs = (tid > 0) ? part[tid - 1] : 0;
    #pragma unroll
    for (int j = 0; j < 4; ++j) {
        int idx = base + j;
        if (idx < S_DEN) { row[idx] = offs + pre[j]; cnt_cur[idx] = offs + pre[j]; }
    }
    if (tid == 1023) row[S_DEN] = part[1023];
}

__global__ void scan_num(int* __restrict__ cnt_cur, int* __restrict__ row) { // 32 blocks × 256
    __shared__ int part[256];
    int b = blockIdx.x, tid = threadIdx.x;
    int c = (tid < S_NUM) ? cnt_cur[b * S_NUM + tid] : 0;
    part[tid] = c; __syncthreads();
    for (int off = 1; off < 256; off <<= 1) {
        int v = (tid >= off) ? part[tid - off] : 0; __syncthreads();
        part[tid] += v; __syncthreads();
    }
    int excl = part[tid] - c;
    if (tid < S_NUM) { row[b * (S_NUM + 1) + tid] = excl; cnt_cur[b * S_NUM + tid] = excl; }
    if (tid == 255) row[b * (S_NUM + 1) + S_NUM] = part[255];
}

// edge payload: {src | pdf<<12, float_bits(exp(logw))} — 8 B/edge
__global__ void scatter_den(const int* __restrict__ src, const int* __restrict__ dst,
                            const int* __restrict__ pdf, const float* __restrict__ logw,
                            int* __restrict__ cur, int2* __restrict__ csr) {
    int e = blockIdx.x * 256 + threadIdx.x;
    if (e >= E_DEN) return;
    int pos = atomicAdd(&cur[dst[e]], 1);
    csr[pos] = make_int2(src[e] | (pdf[e] << 12), __float_as_int(__expf(logw[e])));
}

__global__ void scatter_num(const int* __restrict__ src, const int* __restrict__ dst,
                            const int* __restrict__ pdf, const float* __restrict__ logw,
                            int* __restrict__ cur, int2* __restrict__ csr) { // grid (3,32)
    int b = blockIdx.y, j = blockIdx.x * 256 + threadIdx.x;
    if (j >= E_NUM) return;
    int e = b * E_NUM + j;
    int pos = atomicAdd(&cur[b * S_NUM + dst[e]], 1);
    csr[b * E_NUM + pos] = make_int2(src[e] | (pdf[e] << 12), __float_as_int(__expf(logw[e])));
}

// edge-balanced state partition, weighted so role 7 (num owner) gets less den work
__global__ void part_den(const int* __restrict__ row, int* __restrict__ part) {
    int r = threadIdx.x;                               // 1 block, 16 threads
    if (r > NCHUNK) return;
    if (r == 0)        { part[0] = 0; return; }
    if (r == NCHUNK)   { part[NCHUNK] = S_DEN; return; }
    int target = r * WTGT; if (target > E_DEN) target = E_DEN;
    int lo = 0, hi = S_DEN;
    while (lo < hi) { int mid = (lo + hi) >> 1; if (row[mid] < target) lo = mid + 1; else hi = mid; }
    part[r] = lo;
}

// ===================== persistent forward kernel ============================
// 256 blocks (utt b = bid&31, role r = bid>>5), 512 threads, 1 block/CU.
// Sync path: all cross-block data moves via agent-scope (sc1) atomics that
// bypass L1/L2 to the coherence point -> NO fences/invalidates in the loop.
// Flag {tag, role-max} is release-stored; poll is relaxed; the ex(t+1) LDS
// staging executes between publish and poll to hide the flag round trip.
__global__ __launch_bounds__(NTB, 1)
void chain_persist(const float* __restrict__ x, const int* __restrict__ x_lengths,
                   const int* __restrict__ den_row, const int2* __restrict__ den_csr,
                   const int* __restrict__ part,
                   const int* __restrict__ num_row, const int2* __restrict__ num_csr,
                   const float* __restrict__ den_init, const float* __restrict__ den_final,
                   const float* __restrict__ num_init, const float* __restrict__ num_final,
                   float* __restrict__ EAd,
                   unsigned long long* __restrict__ Mflag,
                   unsigned long long* __restrict__ Fflag,
                   float* __restrict__ ll) {
    __shared__ int2   csr_d[ECAP];         // 123904 B
    __shared__ float4 ex4[D_ / 4];         //  12288 B
    __shared__ float  eal[S_DEN];          //  16000 B
    __shared__ int2   csr_n[E_NUM];        //   4800 B
    __shared__ float  eal_n[S_NUM];        //    800 B
    __shared__ float  red[8], red_n[8];
    __shared__ float  s_m;
    float* ex = (float*)ex4;

    const int tid = threadIdx.x;
    const int b   = blockIdx.x & 31;
    const int r   = blockIdx.x >> 5;
    const int len = x_lengths[b];

    // --- stage den CSR chunk + per-thread row bounds (≤2 states/thread) ---
    const int s0 = part[r], s1 = part[r + 1];
    const int e0 = den_row[s0], e1 = den_row[s1];
    const int ne = e1 - e0;
    for (int i = tid; i < ne; i += NTB) csr_d[i] = den_csr[e0 + i];
    const int sa = s0 + tid, sb = s0 + tid + NTB;
    int ba = 0, eaA = 0, bb = 0, ebB = 0;
    if (sa < s1) { ba = den_row[sa] - e0; eaA = den_row[sa + 1] - e0; }
    if (sb < s1) { bb = den_row[sb] - e0; ebB = den_row[sb + 1] - e0; }
    for (int s = tid; s < S_DEN; s += NTB) eal[s] = __expf(den_init[s]);

    // --- role 7: stage num graph ---
    int nb = 0, neE = 0;
    if (r == NCHUNK - 1) {
        for (int i = tid; i < E_NUM; i += NTB) csr_n[i] = num_csr[b * E_NUM + i];
        if (tid < S_NUM) {
            nb  = num_row[b * (S_NUM + 1) + tid];
            neE = num_row[b * (S_NUM + 1) + tid + 1];
            eal_n[tid] = __expf(num_init[b * S_NUM + tid]);
        }
    }

    // --- prologue: stage ex(0) from x(0); prefetch x(1) ---
    const float* xb = x + (size_t)b * T_ * D_;
    const bool  has2 = tid < (D_ / 4 - NTB);
    float4 xr0, xr1;
    {
        const float4* p = (const float4*)xb;
        xr0 = p[tid];
        xr1 = has2 ? p[tid + NTB] : make_float4(0.f, 0.f, 0.f, 0.f);
        float4 ev;
        ev.x = __expf(fminf(xr0.x, 60.f)); ev.y = __expf(fminf(xr0.y, 60.f));
        ev.z = __expf(fminf(xr0.z, 60.f)); ev.w = __expf(fminf(xr0.w, 60.f));
        ex4[tid] = ev;
        if (has2) {
            float4 e1v;
            e1v.x = __expf(fminf(xr1.x, 60.f)); e1v.y = __expf(fminf(xr1.y, 60.f));
            e1v.z = __expf(fminf(xr1.z, 60.f)); e1v.w = __expf(fminf(xr1.w, 60.f));
            ex4[tid + NTB] = e1v;
        }
        if (len > 1) {
            const float4* pn = (const float4*)(xb + (size_t)D_);
            xr0 = pn[tid];
            if (has2) xr1 = pn[tid + NTB];
        }
    }
    __syncthreads();   // ex(0), eal, csr staged

    float off = 0.f, offn = 0.f, acc0 = 0.f, acc1 = 0.f, accn = 0.f;
    unsigned long long* uflag = Mflag + (size_t)b * FLAGS_PER_UTT;   // [parity][role]

    for (int t = 0; t < len; ++t) {
        // ---- phase B: den gather from LDS ----
        float lmax = 0.f;
        acc0 = 0.f; acc1 = 0.f;
        if (sa < s1) {
            float a0 = 0.f, a1 = 0.f;
            int e = ba;
            for (; e + 2 <= eaA; e += 2) {
                int2 p0 = csr_d[e], p1 = csr_d[e + 1];
                a0 += eal[p0.x & 0xFFF] * __int_as_float(p0.y) * ex[p0.x >> 12];
                a1 += eal[p1.x & 0xFFF] * __int_as_float(p1.y) * ex[p1.x >> 12];
            }
            if (e < eaA) {
                int2 p0 = csr_d[e];
                a0 += eal[p0.x & 0xFFF] * __int_as_float(p0.y) * ex[p0.x >> 12];
            }
            acc0 = a0 + a1; lmax = acc0;
        }
        if (sb < s1) {
            float a0 = 0.f, a1 = 0.f;
            int e = bb;
            for (; e + 2 <= ebB; e += 2) {
                int2 p0 = csr_d[e], p1 = csr_d[e + 1];
                a0 += eal[p0.x & 0xFFF] * __int_as_float(p0.y) * ex[p0.x >> 12];
                a1 += eal[p1.x & 0xFFF] * __int_as_float(p1.y) * ex[p1.x >> 12];
            }
            if (e < ebB) {
                int2 p0 = csr_d[e];
                a0 += eal[p0.x & 0xFFF] * __int_as_float(p0.y) * ex[p0.x >> 12];
            }
            acc1 = a0 + a1; lmax = fmaxf(lmax, acc1);
        }

        // ---- EA_next slice: agent-scope (sc1) stores, straight to L3 ----
        float* EAn_g = EAd + ((size_t)((t + 1) & 1) * B_ + b) * S_DEN;
        if (sa < s1) __hip_atomic_store(&EAn_g[sa], acc0, __ATOMIC_RELAXED, __HIP_MEMORY_SCOPE_AGENT);
        if (sb < s1) __hip_atomic_store(&EAn_g[sb], acc1, __ATOMIC_RELAXED, __HIP_MEMORY_SCOPE_AGENT);

        // ---- num gather (role 7, LDS only) ----
        float lmax_n = 0.f;
        if (r == NCHUNK - 1 && tid < S_NUM) {
            float a = 0.f;
            for (int e = nb; e < neE; ++e) {
                int2 p0 = csr_n[e];
                a += eal_n[p0.x & 0xFFF] * __int_as_float(p0.y) * ex[p0.x >> 12];
            }
            accn = a; lmax_n = a;
        }

        // ---- block reduce den/num maxima ----
        #pragma unroll
        for (int o = 32; o > 0; o >>= 1) {
            lmax   = fmaxf(lmax,   __shfl_down(lmax, o));
            lmax_n = fmaxf(lmax_n, __shfl_down(lmax_n, o));
        }
        if ((tid & 63) == 0) { red[tid >> 6] = lmax; red_n[tid >> 6] = lmax_n; }
        __syncthreads();               // (1) all waves' EA stores acked (vmcnt drain)

        // ---- publish flag {tag=t+1, role max} ASAP ----
        if (t + 1 < len && tid == 0) {
            float bm = red[0];
            #pragma unroll
            for (int w = 1; w < 8; ++w) bm = fmaxf(bm, red[w]);
            unsigned long long pv =
                ((unsigned long long)(unsigned)(t + 1) << 32) |
                (unsigned long long)__float_as_uint(bm);
            __hip_atomic_store(&uflag[(t & 1) * 8 + r], pv,
                               __ATOMIC_RELEASE, __HIP_MEMORY_SCOPE_AGENT);
        }

        // ---- local work to hide the flag round trip ----
        if (r == NCHUNK - 1) {         // num renorm, fully local
            float Mn = red_n[0];
            #pragma unroll
            for (int w = 1; w < 8; ++w) Mn = fmaxf(Mn, red_n[w]);
            if (!(Mn > 0.f)) Mn = 1.f;
            if (tid < S_NUM) eal_n[tid] = accn / Mn;
            offn += __logf(Mn);
        }
        if (t + 1 < len) {
            // stage ex(t+1) from regs; prefetch x(t+2)
            float4 ev;
            ev.x = __expf(fminf(xr0.x, 60.f)); ev.y = __expf(fminf(xr0.y, 60.f));
            ev.z = __expf(fminf(xr0.z, 60.f)); ev.w = __expf(fminf(xr0.w, 60.f));
            ex4[tid] = ev;
            if (has2) {
                float4 e1v;
                e1v.x = __expf(fminf(xr1.x, 60.f)); e1v.y = __expf(fminf(xr1.y, 60.f));
                e1v.z = __expf(fminf(xr1.z, 60.f)); e1v.w = __expf(fminf(xr1.w, 60.f));
                ex4[tid + NTB] = e1v;
            }
            if (t + 2 < len) {
                const float4* pn = (const float4*)(xb + (size_t)(t + 2) * D_);
                xr0 = pn[tid];
                if (has2) xr1 = pn[tid + NTB];
            }

            // ---- poll the 8 role flags (relaxed sc1 loads, no RMW, no fence) ----
            if (tid < 64) {
                unsigned long long* slots = &uflag[(t & 1) * 8];
                float mv = 0.f;
                bool rdy = (tid >= 8);
                const unsigned want = (unsigned)(t + 1);
                while (true) {
                    if (!rdy) {
                        unsigned long long v = __hip_atomic_load(&slots[tid],
                                                 __ATOMIC_RELAXED, __HIP_MEMORY_SCOPE_AGENT);
                        if ((unsigned)(v >> 32) == want) {
                            rdy = true; mv = __uint_as_float((unsigned)v);
                        }
                    }
                    if (__all(rdy)) break;
                    __builtin_amdgcn_s_sleep(1);
                }
                #pragma unroll
                for (int o = 4; o > 0; o >>= 1) mv = fmaxf(mv, __shfl_down(mv, o));
                if (tid == 0) s_m = (mv > 0.f) ? mv : 1.f;
            }
            __syncthreads();           // (2) flag observed by all; s_m visible

            // ---- restage eal from EA_next via sc1 loads (bypass caches) ----
            float M = s_m;
            off += __logf(M);
            float inv = 1.f / M;
            float v[8];
            #pragma unroll
            for (int k = 0; k < 8; ++k) {
                int s = tid + k * NTB;
                v[k] = (s < S_DEN)
                     ? __hip_atomic_load(&EAn_g[s], __ATOMIC_RELAXED, __HIP_MEMORY_SCOPE_AGENT)
                     : 0.f;
            }
            #pragma unroll
            for (int k = 0; k < 8; ++k) {
                int s = tid + k * NTB;
                if (s < S_DEN) eal[s] = v[k] * inv;
            }
            __syncthreads();           // (3) eal + ex(t+1) ready for next gather
        }
    }

    // --- final: den partial from last-step acc regs (un-renormed, matches off) ---
    float fs = 0.f;
    if (sa < s1) fs += acc0 * __expf(den_final[sa]);
    if (sb < s1) fs += acc1 * __expf(den_final[sb]);
    #pragma unroll
    for (int o = 32; o > 0; o >>= 1) fs += __shfl_down(fs, o);
    if ((tid & 63) == 0) red[tid >> 6] = fs;
    __syncthreads();

    if (tid == 0) {
        float bf = 0.f;
        #pragma unroll
        for (int w = 0; w < 8; ++w) bf += red[w];
        unsigned long long pv = ((unsigned long long)(unsigned)len << 32) |
                                (unsigned long long)__float_as_uint(bf);
        __hip_atomic_store(&Fflag[b * 8 + r], pv, __ATOMIC_RELEASE, __HIP_MEMORY_SCOPE_AGENT);
    }

    if (r == 0 && tid < 64) {                  // den ll: role 0 gathers 8 partials
        float sv = 0.f;
        bool rdy = (tid >= 8);
        const unsigned want = (unsigned)len;
        while (true) {
            if (!rdy) {
                unsigned long long v = __hip_atomic_load(&Fflag[b * 8 + tid],
                                         __ATOMIC_RELAXED, __HIP_MEMORY_SCOPE_AGENT);
                if ((unsigned)(v >> 32) == want) { rdy = true; sv = __uint_as_float((unsigned)v); }
            }
            if (__all(rdy)) break;
            __builtin_amdgcn_s_sleep(1);
        }
        #pragma unroll
        for (int o = 4; o > 0; o >>= 1) sv += __shfl_down(sv, o);
        if (tid == 0) ll[b] = __logf(sv) + off;
    }

    if (r == NCHUNK - 1) {                     // num ll: fully local to role 7
        float ns = (tid < S_NUM) ? eal_n[tid] * __expf(num_final[b * S_NUM + tid]) : 0.f;
        #pragma unroll
        for (int o = 32; o > 0; o >>= 1) ns += __shfl_down(ns, o);
        if ((tid & 63) == 0) red_n[tid >> 6] = ns;
        __syncthreads();
        if (tid == 0) {
            float tn = 0.f;
            #pragma unroll
            for (int w = 0; w < 8; ++w) tn += red_n[w];
            ll[B_ + b] = __logf(tn) + offn;
        }
    }
}

// ===================== combine ==============================================
__global__ void finalize_loss(const float* __restrict__ ll, const int* __restrict__ x_lengths,
                              float* __restrict__ out) {
    int tid = threadIdx.x;              // 64 threads, 1 block
    float d = (tid < B_) ? ll[tid] : 0.f;
    float n = (tid < B_) ? ll[B_ + tid] : 0.f;
    float l = (tid < B_) ? (float)x_lengths[tid] : 0.f;
    #pragma unroll
    for (int o = 32; o > 0; o >>= 1) {
        d += __shfl_down(d, o); n += __shfl_down(n, o); l += __shfl_down(l, o);
    }
    if (tid == 0) out[0] = (d - n) / l;
}

// ===================== fallback (no workspace) ==============================
__global__ __launch_bounds__(1024)
void chain_forward_atomic(const float* __restrict__ x, const int* __restrict__ x_lengths,
                          const int* __restrict__ den_src, const int* __restrict__ den_dst,
                          const int* __restrict__ den_pdf, const float* __restrict__ den_logw,
                          const float* __restrict__ den_init, const float* __restrict__ den_final,
                          const int* __restrict__ num_src, const int* __restrict__ num_dst,
                          const int* __restrict__ num_pdf, const float* __restrict__ num_logw,
                          const float* __restrict__ num_init, const float* __restrict__ num_final,
                          float* __restrict__ ll_out) {
    __shared__ float ea[S_DEN];
    __shared__ float ssum[S_DEN];
    __shared__ float ex[D_];
    __shared__ float red[16];
    __shared__ float s_m;
    const int  tid = threadIdx.x;
    const bool is_den = blockIdx.x < B_;
    const int  b = is_den ? blockIdx.x : blockIdx.x - B_;
    const int  S = is_den ? S_DEN : S_NUM;
    const int  E = is_den ? E_DEN : E_NUM;
    const int*   esrc = is_den ? den_src : num_src + b * E_NUM;
    const int*   edst = is_den ? den_dst : num_dst + b * E_NUM;
    const int*   epdf = is_den ? den_pdf : num_pdf + b * E_NUM;
    const float* elw  = is_den ? den_logw: num_logw + b * E_NUM;
    const float* init = is_den ? den_init : num_init + b * S_NUM;
    const float* fin  = is_den ? den_final: num_final + b * S_NUM;
    const int    len  = x_lengths[b];
    const float* xb   = x + (size_t)b * T_ * D_;
    for (int s = tid; s < S; s += 1024) { ea[s] = __expf(init[s]); ssum[s] = 0.f; }
    float off = 0.f;
    for (int t = 0; t < len; ++t) {
        const float4* xr4 = reinterpret_cast<const float4*>(xb + (size_t)t * D_);
        for (int d = tid; d < D_ / 4; d += 1024) {
            float4 v = xr4[d];
            ex[4*d+0] = __expf(fminf(v.x, 60.f)); ex[4*d+1] = __expf(fminf(v.y, 60.f));
            ex[4*d+2] = __expf(fminf(v.z, 60.f)); ex[4*d+3] = __expf(fminf(v.w, 60.f));
        }
        __syncthreads();
        for (int e = tid; e < E; e += 1024)
            unsafeAtomicAdd(&ssum[edst[e]], ea[esrc[e]] * __expf(elw[e]) * ex[epdf[e]]);
        __syncthreads();
        float lm = 0.f;
        for (int s = tid; s < S; s += 1024) lm = fmaxf(lm, ssum[s]);
        #pragma unroll
        for (int o = 32; o > 0; o >>= 1) lm = fmaxf(lm, __shfl_down(lm, o));
        if ((tid & 63) == 0) red[tid >> 6] = lm;
        __syncthreads();
        if (tid == 0) {
            float m = red[0];
            for (int w = 1; w < 16; ++w) m = fmaxf(m, red[w]);
            s_m = (m > 0.f) ? m : 1.f;
        }
        __syncthreads();
        float inv = 1.f / s_m;
        off += __logf(s_m);
        for (int s = tid; s < S; s += 1024) { ea[s] = ssum[s] * inv; ssum[s] = 0.f; }
    }
    float lsum = 0.f;
    for (int s = tid; s < S; s += 1024) lsum += ea[s] * __expf(fin[s]);
    #pragma unroll
    for (int o = 32; o > 0; o >>= 1) lsum += __shfl_down(lsum, o);
    if ((tid & 63) == 0) red[tid >> 6] = lsum;
    __syncthreads();
    if (tid == 0) {
        float tot = 0.f;
        for (int w = 0; w < 16; ++w) tot += red[w];
        ll_out[blockIdx.x] = off + __logf(tot);
    }
}

static inline size_t align16(size_t v) { return (v + 15) & ~size_t(15); }

extern "C" void kernel_launch(void* const* d_in, const int* in_sizes, int n_in,
                              void* d_out, int out_size, void* d_ws, size_t ws_size,
                              hipStream_t stream) {
    const float* x         = (const float*)d_in[0];
    const int*   x_lengths = (const int*)  d_in[1];
    const int*   den_src   = (const int*)  d_in[2];
    const int*   den_dst   = (const int*)  d_in[3];
    const int*   den_pdf   = (const int*)  d_in[4];
    const float* den_logw  = (const float*)d_in[5];
    const float* den_init  = (const float*)d_in[6];
    const float* den_final = (const float*)d_in[7];
    const int*   num_src   = (const int*)  d_in[8];
    const int*   num_dst   = (const int*)  d_in[9];
    const int*   num_pdf   = (const int*)  d_in[10];
    const float* num_logw  = (const float*)d_in[11];
    const float* num_init  = (const float*)d_in[12];
    const float* num_final = (const float*)d_in[13];

    char* ws = (char*)d_ws;
    size_t o = 0;
    float*              ll      = (float*)             (ws + o); o = align16(o + 64 * sizeof(float));
    int*                den_row = (int*)               (ws + o); o = align16(o + (S_DEN + 1) * sizeof(int));
    int*                den_cur = (int*)               (ws + o); o = align16(o + S_DEN * sizeof(int));
    int*                num_row = (int*)               (ws + o); o = align16(o + B_ * (S_NUM + 1) * sizeof(int));
    int*                num_cur = (int*)               (ws + o); o = align16(o + B_ * S_NUM * sizeof(int));
    int2*               den_csr = (int2*)              (ws + o); o = align16(o + (size_t)E_DEN * sizeof(int2));
    int2*               num_csr = (int2*)              (ws + o); o = align16(o + (size_t)B_ * E_NUM * sizeof(int2));
    int*                part    = (int*)               (ws + o); o = align16(o + (NCHUNK + 1) * sizeof(int));
    float*              EAd     = (float*)             (ws + o); o = align16(o + (size_t)2 * B_ * S_DEN * sizeof(float));
    unsigned long long* Mflag   = (unsigned long long*)(ws + o); o = align16(o + (size_t)B_ * FLAGS_PER_UTT * sizeof(unsigned long long));
    unsigned long long* Fflag   = (unsigned long long*)(ws + o); o = align16(o + (size_t)B_ * 8 * sizeof(unsigned long long));
    const size_t need = o;

    if (ws_size >= need) {
        zero_ints<<<(S_DEN + 255) / 256, 256, 0, stream>>>(den_cur, S_DEN);
        zero_ints<<<(B_ * S_NUM + 255) / 256, 256, 0, stream>>>(num_cur, B_ * S_NUM);
        hist_den<<<(E_DEN + 255) / 256, 256, 0, stream>>>(den_dst, den_cur);
        hist_num<<<dim3(3, B_), 256, 0, stream>>>(num_dst, num_cur);
        scan_den<<<1, 1024, 0, stream>>>(den_cur, den_row);
        scan_num<<<B_, 256, 0, stream>>>(num_cur, num_row);
        scatter_den<<<(E_DEN + 255) / 256, 256, 0, stream>>>(
            den_src, den_dst, den_pdf, den_logw, den_cur, den_csr);
        scatter_num<<<dim3(3, B_), 256, 0, stream>>>(
            num_src, num_dst, num_pdf, num_logw, num_cur, num_csr);
        part_den<<<1, 16, 0, stream>>>(den_row, part);

        void* args[] = {
            (void*)&x, (void*)&x_lengths, (void*)&den_row, (void*)&den_csr, (void*)&part,
            (void*)&num_row, (void*)&num_csr, (void*)&den_init, (void*)&den_final,
            (void*)&num_init, (void*)&num_final, (void*)&EAd, (void*)&Mflag,
            (void*)&Fflag, (void*)&ll
        };
        hipError_t err = hipLaunchCooperativeKernel((const void*)chain_persist,
                                                    dim3(B_ * NCHUNK), dim3(NTB),
                                                    args, 0, stream);
        if (err != hipSuccess) {
            // same config, 1 block/CU forced by 158 KB LDS -> de-facto co-resident
            chain_persist<<<dim3(B_ * NCHUNK), dim3(NTB), 0, stream>>>(
                x, x_lengths, den_row, den_csr, part, num_row, num_csr,
                den_init, den_final, num_init, num_final,
                EAd, Mflag, Fflag, ll);
        }
        finalize_loss<<<1, 64, 0, stream>>>(ll, x_lengths, (float*)d_out);
    } else {
        chain_forward_atomic<<<2 * B_, 1024, 0, stream>>>(
            x, x_lengths, den_src, den_dst, den_pdf, den_logw, den_init, den_final,
            num_src, num_dst, num_pdf, num_logw, num_init, num_final, ll);
        finalize_loss<<<1, 64, 0, stream>>>(ll, x_lengths, (float*)d_out);
    }
}

// Round 9
// 3381.110 us; speedup vs baseline: 1.8463x; 1.0859x over previous
//
#include <hip/hip_runtime.h>

constexpr int B_     = 32;
constexpr int T_     = 500;
constexpr int D_     = 3072;
constexpr int S_DEN  = 4000;
constexpr int E_DEN  = 120000;
constexpr int S_NUM  = 200;
constexpr int E_NUM  = 600;
constexpr int NCHUNK = 8;                  // den roles per utt
constexpr int WTGT   = (E_DEN + 2 * E_NUM) / NCHUNK;  // role 7 gets fewer den edges
constexpr int ECAP   = 15488;              // LDS cap (WTGT + row slack)
constexpr int NTB    = 512;                // threads per persistent block

// ============================ CSR build =====================================
__global__ void zero_ints(int* p, int n) {
    int i = blockIdx.x * 256 + threadIdx.x;
    if (i < n) p[i] = 0;
}

__global__ void hist_den(const int* __restrict__ dst, int* __restrict__ cnt) {
    int e = blockIdx.x * 256 + threadIdx.x;
    if (e < E_DEN) atomicAdd(&cnt[dst[e]], 1);
}

__global__ void hist_num(const int* __restrict__ dst, int* __restrict__ cnt) { // grid (3,32)
    int b = blockIdx.y, j = blockIdx.x * 256 + threadIdx.x;
    if (j < E_NUM) atomicAdd(&cnt[b * S_NUM + dst[b * E_NUM + j]], 1);
}

__global__ void scan_den(int* __restrict__ cnt_cur, int* __restrict__ row) { // 1 block, 1024 thr
    __shared__ int part[1024];
    int tid = threadIdx.x, base = tid * 4;
    int c[4], pre[4], s = 0;
    #pragma unroll
    for (int j = 0; j < 4; ++j) {
        int idx = base + j;
        c[j] = (idx < S_DEN) ? cnt_cur[idx] : 0;
        pre[j] = s; s += c[j];
    }
    part[tid] = s; __syncthreads();
    for (int off = 1; off < 1024; off <<= 1) {
        int v = (tid >= off) ? part[tid - off] : 0; __syncthreads();
        part[tid] += v; __syncthreads();
    }
    int offs = (tid > 0) ? part[tid - 1] : 0;
    #pragma unroll
    for (int j = 0; j < 4; ++j) {
        int idx = base + j;
        if (idx < S_DEN) { row[idx] = offs + pre[j]; cnt_cur[idx] = offs + pre[j]; }
    }
    if (tid == 1023) row[S_DEN] = part[1023];
}

__global__ void scan_num(int* __restrict__ cnt_cur, int* __restrict__ row) { // 32 blocks × 256
    __shared__ int part[256];
    int b = blockIdx.x, tid = threadIdx.x;
    int c = (tid < S_NUM) ? cnt_cur[b * S_NUM + tid] : 0;
    part[tid] = c; __syncthreads();
    for (int off = 1; off < 256; off <<= 1) {
        int v = (tid >= off) ? part[tid - off] : 0; __syncthreads();
        part[tid] += v; __syncthreads();
    }
    int excl = part[tid] - c;
    if (tid < S_NUM) { row[b * (S_NUM + 1) + tid] = excl; cnt_cur[b * S_NUM + tid] = excl; }
    if (tid == 255) row[b * (S_NUM + 1) + S_NUM] = part[255];
}

// edge payload: {src | pdf<<12, float_bits(exp(logw))} — 8 B/edge
__global__ void scatter_den(const int* __restrict__ src, const int* __restrict__ dst,
                            const int* __restrict__ pdf, const float* __restrict__ logw,
                            int* __restrict__ cur, int2* __restrict__ csr) {
    int e = blockIdx.x * 256 + threadIdx.x;
    if (e >= E_DEN) return;
    int pos = atomicAdd(&cur[dst[e]], 1);
    csr[pos] = make_int2(src[e] | (pdf[e] << 12), __float_as_int(__expf(logw[e])));
}

__global__ void scatter_num(const int* __restrict__ src, const int* __restrict__ dst,
                            const int* __restrict__ pdf, const float* __restrict__ logw,
                            int* __restrict__ cur, int2* __restrict__ csr) { // grid (3,32)
    int b = blockIdx.y, j = blockIdx.x * 256 + threadIdx.x;
    if (j >= E_NUM) return;
    int e = b * E_NUM + j;
    int pos = atomicAdd(&cur[b * S_NUM + dst[e]], 1);
    csr[b * E_NUM + pos] = make_int2(src[e] | (pdf[e] << 12), __float_as_int(__expf(logw[e])));
}

// edge-balanced state partition, weighted so role 7 (num owner) gets less den work
__global__ void part_den(const int* __restrict__ row, int* __restrict__ part) {
    int r = threadIdx.x;                               // 1 block, 16 threads
    if (r > NCHUNK) return;
    if (r == 0)        { part[0] = 0; return; }
    if (r == NCHUNK)   { part[NCHUNK] = S_DEN; return; }
    int target = r * WTGT; if (target > E_DEN) target = E_DEN;
    int lo = 0, hi = S_DEN;
    while (lo < hi) { int mid = (lo + hi) >> 1; if (row[mid] < target) lo = mid + 1; else hi = mid; }
    part[r] = lo;
}

// ===================== persistent forward kernel ============================
// 256 blocks (utt b = bid&31, role r = bid>>5), 512 threads, 1 block/CU.
// Cross-block exchange: each state's value is an 8B packet {tag=t+1, fp32}
// written ONCE with a relaxed agent-scope store; readers poll the packets
// directly (data carries its own readiness). No flags, no fences, no store-
// drain before publish: ONE cross-CU round trip per step. Every block
// recomputes M = max over the 4000 loaded values (order-independent -> bit-
// identical across blocks); renorm is folded in lagged: acc = raw * inv_prev.
__global__ __launch_bounds__(NTB, 1)
void chain_persist(const float* __restrict__ x, const int* __restrict__ x_lengths,
                   const int* __restrict__ den_row, const int2* __restrict__ den_csr,
                   const int* __restrict__ part,
                   const int* __restrict__ num_row, const int2* __restrict__ num_csr,
                   const float* __restrict__ den_init, const float* __restrict__ den_final,
                   const float* __restrict__ num_init, const float* __restrict__ num_final,
                   unsigned long long* __restrict__ EAslot,   // [2][B][S_DEN]
                   unsigned long long* __restrict__ Fflag,    // [B][8]
                   float* __restrict__ ll) {
    __shared__ int2   csr_d[ECAP];         // 123904 B
    __shared__ float4 ex4[D_ / 4];         //  12288 B
    __shared__ float  eal[S_DEN];          //  16000 B (raw v_t values)
    __shared__ int2   csr_n[E_NUM];        //   4800 B
    __shared__ float  eal_n[S_NUM];        //    800 B
    __shared__ float  red[8], red_n[8];
    float* ex = (float*)ex4;

    const int tid = threadIdx.x;
    const int b   = blockIdx.x & 31;
    const int r   = blockIdx.x >> 5;
    const int len = x_lengths[b];

    // --- stage den CSR chunk + per-thread row bounds (≤2 states/thread) ---
    const int s0 = part[r], s1 = part[r + 1];
    const int e0 = den_row[s0], e1 = den_row[s1];
    const int ne = e1 - e0;
    for (int i = tid; i < ne; i += NTB) csr_d[i] = den_csr[e0 + i];
    const int sa = s0 + tid, sb = s0 + tid + NTB;
    int ba = 0, eaA = 0, bb = 0, ebB = 0;
    if (sa < s1) { ba = den_row[sa] - e0; eaA = den_row[sa + 1] - e0; }
    if (sb < s1) { bb = den_row[sb] - e0; ebB = den_row[sb + 1] - e0; }
    for (int s = tid; s < S_DEN; s += NTB) eal[s] = __expf(den_init[s]);

    // --- role 7: stage num graph ---
    int nb = 0, neE = 0;
    if (r == NCHUNK - 1) {
        for (int i = tid; i < E_NUM; i += NTB) csr_n[i] = num_csr[b * E_NUM + i];
        if (tid < S_NUM) {
            nb  = num_row[b * (S_NUM + 1) + tid];
            neE = num_row[b * (S_NUM + 1) + tid + 1];
            eal_n[tid] = __expf(num_init[b * S_NUM + tid]);
        }
    }

    // --- prologue: stage ex(0); prefetch x(1) ---
    const float* xb = x + (size_t)b * T_ * D_;
    const bool  has2 = tid < (D_ / 4 - NTB);
    float4 xr0, xr1;
    {
        const float4* p = (const float4*)xb;
        xr0 = p[tid];
        xr1 = has2 ? p[tid + NTB] : make_float4(0.f, 0.f, 0.f, 0.f);
        float4 ev;
        ev.x = __expf(fminf(xr0.x, 60.f)); ev.y = __expf(fminf(xr0.y, 60.f));
        ev.z = __expf(fminf(xr0.z, 60.f)); ev.w = __expf(fminf(xr0.w, 60.f));
        ex4[tid] = ev;
        if (has2) {
            float4 e1v;
            e1v.x = __expf(fminf(xr1.x, 60.f)); e1v.y = __expf(fminf(xr1.y, 60.f));
            e1v.z = __expf(fminf(xr1.z, 60.f)); e1v.w = __expf(fminf(xr1.w, 60.f));
            ex4[tid + NTB] = e1v;
        }
        if (len > 1) {
            const float4* pn = (const float4*)(xb + (size_t)D_);
            xr0 = pn[tid];
            if (has2) xr1 = pn[tid + NTB];
        }
    }
    __syncthreads();   // ex(0), eal, csr staged

    float off = 0.f, offn = 0.f, acc0 = 0.f, acc1 = 0.f, accn = 0.f;
    float inv_prev = 1.f;

    for (int t = 0; t < len; ++t) {
        // ---- phase 1: den gather (raw, LDS-resident) ----
        float raw0 = 0.f, raw1 = 0.f;
        if (sa < s1) {
            float a0 = 0.f, a1 = 0.f;
            int e = ba;
            for (; e + 2 <= eaA; e += 2) {
                int2 p0 = csr_d[e], p1 = csr_d[e + 1];
                a0 += eal[p0.x & 0xFFF] * __int_as_float(p0.y) * ex[p0.x >> 12];
                a1 += eal[p1.x & 0xFFF] * __int_as_float(p1.y) * ex[p1.x >> 12];
            }
            if (e < eaA) {
                int2 p0 = csr_d[e];
                a0 += eal[p0.x & 0xFFF] * __int_as_float(p0.y) * ex[p0.x >> 12];
            }
            raw0 = a0 + a1;
        }
        if (sb < s1) {
            float a0 = 0.f, a1 = 0.f;
            int e = bb;
            for (; e + 2 <= ebB; e += 2) {
                int2 p0 = csr_d[e], p1 = csr_d[e + 1];
                a0 += eal[p0.x & 0xFFF] * __int_as_float(p0.y) * ex[p0.x >> 12];
                a1 += eal[p1.x & 0xFFF] * __int_as_float(p1.y) * ex[p1.x >> 12];
            }
            if (e < ebB) {
                int2 p0 = csr_d[e];
                a0 += eal[p0.x & 0xFFF] * __int_as_float(p0.y) * ex[p0.x >> 12];
            }
            raw1 = a0 + a1;
        }
        acc0 = raw0 * inv_prev;
        acc1 = raw1 * inv_prev;

        // ---- phase 2: publish {tag,value} packets (one relaxed sc1 store) ----
        if (t + 1 < len) {
            unsigned long long* slw = EAslot + ((size_t)(t & 1) * B_ + b) * S_DEN;
            const unsigned long long tg = (unsigned long long)(unsigned)(t + 1) << 32;
            if (sa < s1)
                __hip_atomic_store(&slw[sa], tg | __float_as_uint(acc0),
                                   __ATOMIC_RELAXED, __HIP_MEMORY_SCOPE_AGENT);
            if (sb < s1)
                __hip_atomic_store(&slw[sb], tg | __float_as_uint(acc1),
                                   __ATOMIC_RELAXED, __HIP_MEMORY_SCOPE_AGENT);
        }

        // ---- phase 3: num gather (role 7, LDS only) + its max ----
        float lmax_n = 0.f;
        if (r == NCHUNK - 1) {
            if (tid < S_NUM) {
                float a = 0.f;
                for (int e = nb; e < neE; ++e) {
                    int2 p0 = csr_n[e];
                    a += eal_n[p0.x & 0xFFF] * __int_as_float(p0.y) * ex[p0.x >> 12];
                }
                accn = a; lmax_n = a;
            }
            #pragma unroll
            for (int o = 32; o > 0; o >>= 1) lmax_n = fmaxf(lmax_n, __shfl_down(lmax_n, o));
            if ((tid & 63) == 0) red_n[tid >> 6] = lmax_n;
        }
        __syncthreads();               // barrier A: all gather reads of eal/ex done

        if (r == NCHUNK - 1) {         // num renorm (local)
            float Mn = red_n[0];
            #pragma unroll
            for (int w = 1; w < 8; ++w) Mn = fmaxf(Mn, red_n[w]);
            if (!(Mn > 0.f)) Mn = 1.f;
            if (tid < S_NUM) eal_n[tid] = accn / Mn;
            offn += __logf(Mn);
        }

        if (t + 1 < len) {
            // ---- phase 4: stage ex(t+1); prefetch x(t+2) (overlaps the poll RT) ----
            float4 ev;
            ev.x = __expf(fminf(xr0.x, 60.f)); ev.y = __expf(fminf(xr0.y, 60.f));
            ev.z = __expf(fminf(xr0.z, 60.f)); ev.w = __expf(fminf(xr0.w, 60.f));
            ex4[tid] = ev;
            if (has2) {
                float4 e1v;
                e1v.x = __expf(fminf(xr1.x, 60.f)); e1v.y = __expf(fminf(xr1.y, 60.f));
                e1v.z = __expf(fminf(xr1.z, 60.f)); e1v.w = __expf(fminf(xr1.w, 60.f));
                ex4[tid + NTB] = e1v;
            }
            if (t + 2 < len) {
                const float4* pn = (const float4*)(xb + (size_t)(t + 2) * D_);
                xr0 = pn[tid];
                if (has2) xr1 = pn[tid + NTB];
            }

            // ---- phase 5: poll packets, restage eal (raw), local max ----
            const unsigned long long* slr = EAslot + ((size_t)(t & 1) * B_ + b) * S_DEN;
            const unsigned want = (unsigned)(t + 1);
            float mv = 0.f;
            unsigned rdy = 0;
            while (rdy != 0xFFu) {
                #pragma unroll
                for (int k = 0; k < 8; ++k) {
                    if (rdy & (1u << k)) continue;
                    int s = tid + k * NTB;
                    if (s >= S_DEN) { rdy |= 1u << k; continue; }
                    unsigned long long v = __hip_atomic_load(&slr[s],
                                             __ATOMIC_RELAXED, __HIP_MEMORY_SCOPE_AGENT);
                    if ((unsigned)(v >> 32) == want) {
                        float f = __uint_as_float((unsigned)v);
                        eal[s] = f;
                        mv = fmaxf(mv, f);
                        rdy |= 1u << k;
                    }
                }
                if (rdy != 0xFFu) __builtin_amdgcn_s_sleep(1);
            }
            #pragma unroll
            for (int o = 32; o > 0; o >>= 1) mv = fmaxf(mv, __shfl_down(mv, o));
            if ((tid & 63) == 0) red[tid >> 6] = mv;
            __syncthreads();           // barrier B: eal/ex(t+1)/red ready

            float M = red[0];
            #pragma unroll
            for (int w = 1; w < 8; ++w) M = fmaxf(M, red[w]);
            if (!(M > 0.f)) M = 1.f;
            off += __logf(M);
            inv_prev = 1.f / M;
        }
    }

    // --- epilogue: den partial from last acc regs (scaled; consistent with off) ---
    float fs = 0.f;
    if (sa < s1) fs += acc0 * __expf(den_final[sa]);
    if (sb < s1) fs += acc1 * __expf(den_final[sb]);
    #pragma unroll
    for (int o = 32; o > 0; o >>= 1) fs += __shfl_down(fs, o);
    if ((tid & 63) == 0) red[tid >> 6] = fs;
    __syncthreads();

    if (tid == 0) {
        float bf = 0.f;
        #pragma unroll
        for (int w = 0; w < 8; ++w) bf += red[w];
        unsigned long long pv = ((unsigned long long)(unsigned)len << 32) |
                                (unsigned long long)__float_as_uint(bf);
        __hip_atomic_store(&Fflag[b * 8 + r], pv, __ATOMIC_RELAXED, __HIP_MEMORY_SCOPE_AGENT);
    }

    if (r == 0 && tid < 64) {                  // den ll: role 0 gathers 8 partials
        float sv = 0.f;
        bool rdy = (tid >= 8);
        const unsigned want = (unsigned)len;
        while (true) {
            if (!rdy) {
                unsigned long long v = __hip_atomic_load(&Fflag[b * 8 + tid],
                                         __ATOMIC_RELAXED, __HIP_MEMORY_SCOPE_AGENT);
                if ((unsigned)(v >> 32) == want) { rdy = true; sv = __uint_as_float((unsigned)v); }
            }
            if (__all(rdy)) break;
            __builtin_amdgcn_s_sleep(1);
        }
        #pragma unroll
        for (int o = 4; o > 0; o >>= 1) sv += __shfl_down(sv, o);
        if (tid == 0) ll[b] = __logf(sv) + off;
    }

    if (r == NCHUNK - 1) {                     // num ll: fully local to role 7
        float ns = (tid < S_NUM) ? eal_n[tid] * __expf(num_final[b * S_NUM + tid]) : 0.f;
        #pragma unroll
        for (int o = 32; o > 0; o >>= 1) ns += __shfl_down(ns, o);
        if ((tid & 63) == 0) red_n[tid >> 6] = ns;
        __syncthreads();
        if (tid == 0) {
            float tn = 0.f;
            #pragma unroll
            for (int w = 0; w < 8; ++w) tn += red_n[w];
            ll[B_ + b] = __logf(tn) + offn;
        }
    }
}

// ===================== combine ==============================================
__global__ void finalize_loss(const float* __restrict__ ll, const int* __restrict__ x_lengths,
                              float* __restrict__ out) {
    int tid = threadIdx.x;              // 64 threads, 1 block
    float d = (tid < B_) ? ll[tid] : 0.f;
    float n = (tid < B_) ? ll[B_ + tid] : 0.f;
    float l = (tid < B_) ? (float)x_lengths[tid] : 0.f;
    #pragma unroll
    for (int o = 32; o > 0; o >>= 1) {
        d += __shfl_down(d, o); n += __shfl_down(n, o); l += __shfl_down(l, o);
    }
    if (tid == 0) out[0] = (d - n) / l;
}

// ===================== fallback (no workspace) ==============================
__global__ __launch_bounds__(1024)
void chain_forward_atomic(const float* __restrict__ x, const int* __restrict__ x_lengths,
                          const int* __restrict__ den_src, const int* __restrict__ den_dst,
                          const int* __restrict__ den_pdf, const float* __restrict__ den_logw,
                          const float* __restrict__ den_init, const float* __restrict__ den_final,
                          const int* __restrict__ num_src, const int* __restrict__ num_dst,
                          const int* __restrict__ num_pdf, const float* __restrict__ num_logw,
                          const float* __restrict__ num_init, const float* __restrict__ num_final,
                          float* __restrict__ ll_out) {
    __shared__ float ea[S_DEN];
    __shared__ float ssum[S_DEN];
    __shared__ float ex[D_];
    __shared__ float red[16];
    __shared__ float s_m;
    const int  tid = threadIdx.x;
    const bool is_den = blockIdx.x < B_;
    const int  b = is_den ? blockIdx.x : blockIdx.x - B_;
    const int  S = is_den ? S_DEN : S_NUM;
    const int  E = is_den ? E_DEN : E_NUM;
    const int*   esrc = is_den ? den_src : num_src + b * E_NUM;
    const int*   edst = is_den ? den_dst : num_dst + b * E_NUM;
    const int*   epdf = is_den ? den_pdf : num_pdf + b * E_NUM;
    const float* elw  = is_den ? den_logw: num_logw + b * E_NUM;
    const float* init = is_den ? den_init : num_init + b * S_NUM;
    const float* fin  = is_den ? den_final: num_final + b * S_NUM;
    const int    len  = x_lengths[b];
    const float* xb   = x + (size_t)b * T_ * D_;
    for (int s = tid; s < S; s += 1024) { ea[s] = __expf(init[s]); ssum[s] = 0.f; }
    float off = 0.f;
    for (int t = 0; t < len; ++t) {
        const float4* xr4 = reinterpret_cast<const float4*>(xb + (size_t)t * D_);
        for (int d = tid; d < D_ / 4; d += 1024) {
            float4 v = xr4[d];
            ex[4*d+0] = __expf(fminf(v.x, 60.f)); ex[4*d+1] = __expf(fminf(v.y, 60.f));
            ex[4*d+2] = __expf(fminf(v.z, 60.f)); ex[4*d+3] = __expf(fminf(v.w, 60.f));
        }
        __syncthreads();
        for (int e = tid; e < E; e += 1024)
            unsafeAtomicAdd(&ssum[edst[e]], ea[esrc[e]] * __expf(elw[e]) * ex[epdf[e]]);
        __syncthreads();
        float lm = 0.f;
        for (int s = tid; s < S; s += 1024) lm = fmaxf(lm, ssum[s]);
        #pragma unroll
        for (int o = 32; o > 0; o >>= 1) lm = fmaxf(lm, __shfl_down(lm, o));
        if ((tid & 63) == 0) red[tid >> 6] = lm;
        __syncthreads();
        if (tid == 0) {
            float m = red[0];
            for (int w = 1; w < 16; ++w) m = fmaxf(m, red[w]);
            s_m = (m > 0.f) ? m : 1.f;
        }
        __syncthreads();
        float inv = 1.f / s_m;
        off += __logf(s_m);
        for (int s = tid; s < S; s += 1024) { ea[s] = ssum[s] * inv; ssum[s] = 0.f; }
    }
    float lsum = 0.f;
    for (int s = tid; s < S; s += 1024) lsum += ea[s] * __expf(fin[s]);
    #pragma unroll
    for (int o = 32; o > 0; o >>= 1) lsum += __shfl_down(lsum, o);
    if ((tid & 63) == 0) red[tid >> 6] = lsum;
    __syncthreads();
    if (tid == 0) {
        float tot = 0.f;
        for (int w = 0; w < 16; ++w) tot += red[w];
        ll_out[blockIdx.x] = off + __logf(tot);
    }
}

static inline size_t align16(size_t v) { return (v + 15) & ~size_t(15); }

extern "C" void kernel_launch(void* const* d_in, const int* in_sizes, int n_in,
                              void* d_out, int out_size, void* d_ws, size_t ws_size,
                              hipStream_t stream) {
    const float* x         = (const float*)d_in[0];
    const int*   x_lengths = (const int*)  d_in[1];
    const int*   den_src   = (const int*)  d_in[2];
    const int*   den_dst   = (const int*)  d_in[3];
    const int*   den_pdf   = (const int*)  d_in[4];
    const float* den_logw  = (const float*)d_in[5];
    const float* den_init  = (const float*)d_in[6];
    const float* den_final = (const float*)d_in[7];
    const int*   num_src   = (const int*)  d_in[8];
    const int*   num_dst   = (const int*)  d_in[9];
    const int*   num_pdf   = (const int*)  d_in[10];
    const float* num_logw  = (const float*)d_in[11];
    const float* num_init  = (const float*)d_in[12];
    const float* num_final = (const float*)d_in[13];

    char* ws = (char*)d_ws;
    size_t o = 0;
    float*              ll      = (float*)             (ws + o); o = align16(o + 64 * sizeof(float));
    int*                den_row = (int*)               (ws + o); o = align16(o + (S_DEN + 1) * sizeof(int));
    int*                den_cur = (int*)               (ws + o); o = align16(o + S_DEN * sizeof(int));
    int*                num_row = (int*)               (ws + o); o = align16(o + B_ * (S_NUM + 1) * sizeof(int));
    int*                num_cur = (int*)               (ws + o); o = align16(o + B_ * S_NUM * sizeof(int));
    int2*               den_csr = (int2*)              (ws + o); o = align16(o + (size_t)E_DEN * sizeof(int2));
    int2*               num_csr = (int2*)              (ws + o); o = align16(o + (size_t)B_ * E_NUM * sizeof(int2));
    int*                part    = (int*)               (ws + o); o = align16(o + (NCHUNK + 1) * sizeof(int));
    unsigned long long* EAslot  = (unsigned long long*)(ws + o); o = align16(o + (size_t)2 * B_ * S_DEN * sizeof(unsigned long long));
    unsigned long long* Fflag   = (unsigned long long*)(ws + o); o = align16(o + (size_t)B_ * 8 * sizeof(unsigned long long));
    const size_t need = o;

    if (ws_size >= need) {
        zero_ints<<<(S_DEN + 255) / 256, 256, 0, stream>>>(den_cur, S_DEN);
        zero_ints<<<(B_ * S_NUM + 255) / 256, 256, 0, stream>>>(num_cur, B_ * S_NUM);
        hist_den<<<(E_DEN + 255) / 256, 256, 0, stream>>>(den_dst, den_cur);
        hist_num<<<dim3(3, B_), 256, 0, stream>>>(num_dst, num_cur);
        scan_den<<<1, 1024, 0, stream>>>(den_cur, den_row);
        scan_num<<<B_, 256, 0, stream>>>(num_cur, num_row);
        scatter_den<<<(E_DEN + 255) / 256, 256, 0, stream>>>(
            den_src, den_dst, den_pdf, den_logw, den_cur, den_csr);
        scatter_num<<<dim3(3, B_), 256, 0, stream>>>(
            num_src, num_dst, num_pdf, num_logw, num_cur, num_csr);
        part_den<<<1, 16, 0, stream>>>(den_row, part);

        void* args[] = {
            (void*)&x, (void*)&x_lengths, (void*)&den_row, (void*)&den_csr, (void*)&part,
            (void*)&num_row, (void*)&num_csr, (void*)&den_init, (void*)&den_final,
            (void*)&num_init, (void*)&num_final, (void*)&EAslot,
            (void*)&Fflag, (void*)&ll
        };
        hipError_t err = hipLaunchCooperativeKernel((const void*)chain_persist,
                                                    dim3(B_ * NCHUNK), dim3(NTB),
                                                    args, 0, stream);
        if (err != hipSuccess) {
            // same config, 1 block/CU forced by 158 KB LDS -> de-facto co-resident
            chain_persist<<<dim3(B_ * NCHUNK), dim3(NTB), 0, stream>>>(
                x, x_lengths, den_row, den_csr, part, num_row, num_csr,
                den_init, den_final, num_init, num_final,
                EAslot, Fflag, ll);
        }
        finalize_loss<<<1, 64, 0, stream>>>(ll, x_lengths, (float*)d_out);
    } else {
        chain_forward_atomic<<<2 * B_, 1024, 0, stream>>>(
            x, x_lengths, den_src, den_dst, den_pdf, den_logw, den_init, den_final,
            num_src, num_dst, num_pdf, num_logw, num_init, num_final, ll);
        finalize_loss<<<1, 64, 0, stream>>>(ll, x_lengths, (float*)d_out);
    }
}